// Round 15
// baseline (451.051 us; speedup 1.0000x reference)
//
#include <hip/hip_runtime.h>
#include <hip/hip_bf16.h>

// ---------------- problem constants ----------------
#define BB 2
#define TT 2048
#define DD 1024
#define FF 4096
#define VV 256
#define HH 16
#define HD 64
#define MM (BB * TT)      // 4096 rows
#define LOCAL_W 128
#define STRIDE_G 256
#define QS 3072           // fused QKV row stride

typedef short s16x8 __attribute__((ext_vector_type(8)));
typedef __bf16 bf16x8 __attribute__((ext_vector_type(8)));
typedef float f32x4 __attribute__((ext_vector_type(4)));

__device__ __forceinline__ float b2f(unsigned short u) {
  return __builtin_bit_cast(float, (unsigned int)u << 16);
}
__device__ __forceinline__ unsigned short f2b(float f) {
  __hip_bfloat16 h = __float2bfloat16(f);  // RNE
  return __builtin_bit_cast(unsigned short, h);
}
// async global->LDS, 16B per lane; LDS dest = wave-uniform base + lane*16
__device__ __forceinline__ void gl_lds16(const unsigned short* g, unsigned short* l) {
  __builtin_amdgcn_global_load_lds(
      (const __attribute__((address_space(1))) void*)g,
      (__attribute__((address_space(3))) void*)l, 16, 0, 0);
}
__device__ __forceinline__ bf16x8 ldsr(const unsigned short* p) {
  return __builtin_bit_cast(bf16x8, *(const s16x8*)p);
}

// ------- batched weight transpose f32[K][N] -> bf16[N][K], z = batch -------
__global__ __launch_bounds__(256) void transpose_k(const float* __restrict__ W,
                                                   unsigned short* __restrict__ WT,
                                                   int K, int N,
                                                   size_t sstride, size_t dstride) {
  __shared__ float t[32][33];
  const int z = blockIdx.z;
  W += (size_t)z * sstride;
  WT += (size_t)z * dstride;
  const int n0 = blockIdx.x * 32, k0 = blockIdx.y * 32;
  const int tx = threadIdx.x, ty = threadIdx.y;  // (32, 8)
  for (int r = ty; r < 32; r += 8) t[r][tx] = W[(size_t)(k0 + r) * N + n0 + tx];
  __syncthreads();
  for (int r = ty; r < 32; r += 8)
    WT[(size_t)(n0 + r) * K + k0 + tx] = f2b(t[tx][r]);
}

// ------- QKV transpose: z in 0..5 = (layer, which) -> WqkvT[l][3DD][DD] ----
__global__ __launch_bounds__(256) void qkv_t(const float* __restrict__ Wq,
                                             const float* __restrict__ Wk,
                                             const float* __restrict__ Wv,
                                             unsigned short* __restrict__ WT) {
  __shared__ float t[32][33];
  const int z = blockIdx.z;
  const int l = z / 3, which = z % 3;
  const float* W = (which == 0 ? Wq : which == 1 ? Wk : Wv) + (size_t)l * DD * DD;
  unsigned short* D = WT + ((size_t)l * QS + which * DD) * DD;
  const int n0 = blockIdx.x * 32, k0 = blockIdx.y * 32;
  const int tx = threadIdx.x, ty = threadIdx.y;
  for (int r = ty; r < 32; r += 8) t[r][tx] = W[(size_t)(k0 + r) * DD + n0 + tx];
  __syncthreads();
  for (int r = ty; r < 32; r += 8)
    D[(size_t)(n0 + r) * DD + k0 + tx] = f2b(t[tx][r]);
}

// ---------------- concat QKV bias: bcat[l][3072] ----------------
__global__ __launch_bounds__(256) void concat_bias(const float* __restrict__ bq,
                                                   const float* __restrict__ bk,
                                                   const float* __restrict__ bv,
                                                   float* __restrict__ bcat) {
  const int i = blockIdx.x * 256 + threadIdx.x;  // 6144 total
  const int l = i / QS, j = i - l * QS;
  float v;
  if (j < DD) v = bq[l * DD + j];
  else if (j < 2 * DD) v = bk[l * DD + j - DD];
  else v = bv[l * DD + j - 2 * DD];
  bcat[i] = v;
}

// ------- fused embedding + positional + layer-0 LN1 (h + hn out) -----------
__global__ __launch_bounds__(256) void embed_ln(const int* __restrict__ x,
                                                const float* __restrict__ emb,
                                                const float* __restrict__ pos,
                                                const float* __restrict__ g,
                                                const float* __restrict__ be,
                                                float* __restrict__ h,
                                                unsigned short* __restrict__ out) {
  const int row = blockIdx.x;
  const int tid = threadIdx.x;
  const int tok = x[row];
  const int t = row & (TT - 1);
  f32x4 v = *(const f32x4*)&emb[(size_t)tok * DD + tid * 4];
  v += *(const f32x4*)&pos[(size_t)t * DD + tid * 4];
  *(f32x4*)&h[(size_t)row * DD + tid * 4] = v;
  float s = v[0] + v[1] + v[2] + v[3];
  float sq = v[0] * v[0] + v[1] * v[1] + v[2] * v[2] + v[3] * v[3];
#pragma unroll
  for (int off = 32; off; off >>= 1) {
    s += __shfl_xor(s, off);
    sq += __shfl_xor(sq, off);
  }
  __shared__ float ss[4], ssq[4];
  const int w = tid >> 6, lane = tid & 63;
  if (lane == 0) { ss[w] = s; ssq[w] = sq; }
  __syncthreads();
  s = ss[0] + ss[1] + ss[2] + ss[3];
  sq = ssq[0] + ssq[1] + ssq[2] + ssq[3];
  const float mean = s * (1.0f / DD);
  const float var = sq * (1.0f / DD) - mean * mean;
  const float rstd = rsqrtf(var + 1e-5f);
  const float4 gv = *(const float4*)&g[tid * 4];
  const float4 bv = *(const float4*)&be[tid * 4];
  ushort4 o;
  o.x = f2b((v[0] - mean) * rstd * gv.x + bv.x);
  o.y = f2b((v[1] - mean) * rstd * gv.y + bv.y);
  o.z = f2b((v[2] - mean) * rstd * gv.z + bv.z);
  o.w = f2b((v[3] - mean) * rstd * gv.w + bv.w);
  *(ushort4*)&out[(size_t)row * DD + tid * 4] = o;
}

// ---- fused split-K reduce + residual + LayerNorm ----
__global__ __launch_bounds__(256) void ln_red(float* __restrict__ hio,
                                              const float* __restrict__ parts,
                                              const float* __restrict__ bias,
                                              const float* __restrict__ g,
                                              const float* __restrict__ be,
                                              unsigned short* __restrict__ out) {
  const int row = blockIdx.x;
  const int tid = threadIdx.x;
  const size_t base = (size_t)row * DD + tid * 4;
  f32x4 v = *(const f32x4*)&hio[base];
  v += *(const f32x4*)&bias[tid * 4];
  v += *(const f32x4*)&parts[base];
  v += *(const f32x4*)&parts[(size_t)MM * DD + base];
  *(f32x4*)&hio[base] = v;
  float s = v[0] + v[1] + v[2] + v[3];
  float sq = v[0] * v[0] + v[1] * v[1] + v[2] * v[2] + v[3] * v[3];
#pragma unroll
  for (int off = 32; off; off >>= 1) {
    s += __shfl_xor(s, off);
    sq += __shfl_xor(sq, off);
  }
  __shared__ float ss[4], ssq[4];
  const int w = tid >> 6, lane = tid & 63;
  if (lane == 0) { ss[w] = s; ssq[w] = sq; }
  __syncthreads();
  s = ss[0] + ss[1] + ss[2] + ss[3];
  sq = ssq[0] + ssq[1] + ssq[2] + ssq[3];
  const float mean = s * (1.0f / DD);
  const float var = sq * (1.0f / DD) - mean * mean;
  const float rstd = rsqrtf(var + 1e-5f);
  const float4 gv = *(const float4*)&g[tid * 4];
  const float4 bv = *(const float4*)&be[tid * 4];
  ushort4 o;
  o.x = f2b((v[0] - mean) * rstd * gv.x + bv.x);
  o.y = f2b((v[1] - mean) * rstd * gv.y + bv.y);
  o.z = f2b((v[2] - mean) * rstd * gv.z + bv.z);
  o.w = f2b((v[3] - mean) * rstd * gv.w + bv.w);
  *(ushort4*)&out[(size_t)row * DD + tid * 4] = o;
}

// ---------- m97-structure GEMM: 256 thr / 4 waves / 128x128 / BK=32 --------
// Simple 2-barrier K-loop; throughput comes from 3-4 blocks/CU cross-block
// overlap (m114). Chunk-XOR swizzle (0 bank conflicts), 2-D XCD region map
// (g_m=4 x g_n=2; per-XCD L2 working set minimized). Wave tile 64x64.
// EPI: 0 = f32 split-K partial @ out + ks*M*N; 1 = bf16+bias; 3 = bf16 GELU.
template <int EPI>
__global__ __launch_bounds__(256, 4) void gemm_m(const unsigned short* __restrict__ A,
                                                 const unsigned short* __restrict__ BT,
                                                 const float* __restrict__ bias,
                                                 void* __restrict__ outp,
                                                 int M, int N, int K,
                                                 int nbx, int nby, int ksplit,
                                                 int ksub) {
  __shared__ __align__(16) unsigned short lds[8192];  // A[128x32] | B[128x32]
  const int tid = threadIdx.x;
  const int lane = tid & 63;
  const int w = tid >> 6;  // 0..3
  // 2-D XCD region mapping (g_m=4, g_n=2), m-inner within region
  const int o = blockIdx.x;
  const int xcd = o & 7;
  const int j = o >> 3;
  const int m_per = (nby * ksplit) >> 2;
  const int n_per = nbx >> 1;
  const int m_loc = j % m_per, n_loc = j / m_per;
  const int m_idx = (xcd >> 1) * m_per + m_loc;
  const int n_idx = (xcd & 1) * n_per + n_loc;
  const int ks = m_idx / nby;
  const int mp = m_idx - ks * nby;
  const int n0 = n_idx * 128;
  const int m0 = mp * 128;
  const int kb = ks * ksub;
  const int wm = w >> 1, wn = w & 1;  // wave tile: 64 x 64
  f32x4 acc[4][4] = {};

  // staging: 2 A chunks + 2 B chunks per thread (16B each), source pre-swizzled
  const unsigned short* aSrc[2];
  const unsigned short* bSrc[2];
  int dstO[2];
#pragma unroll
  for (int i = 0; i < 2; i++) {
    const int s = tid + (i << 8);          // chunk 0..511
    const int row = s >> 2, sc = s & 3;
    const int l = sc ^ ((row >> 1) & 3);
    aSrc[i] = &A[(size_t)(m0 + row) * K + kb + l * 8];
    bSrc[i] = &BT[(size_t)(n0 + row) * K + kb + l * 8];
    dstO[i] = s * 8;                       // shorts
  }

  const int rA = lane & 15, cr = lane >> 4;
  const int rowA0 = wm * 64 + rA;
  const int rowB0 = wn * 64 + rA;
  const int aAddr0 = rowA0 * 32 + ((cr ^ ((rowA0 >> 1) & 3)) << 3);
  const int bAddr0 = 4096 + rowB0 * 32 + ((cr ^ ((rowB0 >> 1) & 3)) << 3);

  const int NT = ksub >> 5;
  for (int t = 0; t < NT; ++t) {
    if (t) __syncthreads();                // protect LDS from overwrite
    const int kt = t << 5;
#pragma unroll
    for (int i = 0; i < 2; i++) {
      gl_lds16(aSrc[i] + kt, &lds[dstO[i]]);
      gl_lds16(bSrc[i] + kt, &lds[4096 + dstO[i]]);
    }
    __syncthreads();                       // drains vmcnt(0)
    bf16x8 af[4], bfr[4];
#pragma unroll
    for (int m = 0; m < 4; m++) af[m] = ldsr(&lds[aAddr0 + m * 512]);
#pragma unroll
    for (int n = 0; n < 4; n++) bfr[n] = ldsr(&lds[bAddr0 + n * 512]);
#pragma unroll
    for (int m = 0; m < 4; m++)
#pragma unroll
      for (int n = 0; n < 4; n++)
        acc[m][n] = __builtin_amdgcn_mfma_f32_16x16x32_bf16(af[m], bfr[n], acc[m][n], 0, 0, 0);
  }

  const int r0 = (lane >> 4) * 4;
  const int cc = lane & 15;
#pragma unroll
  for (int m = 0; m < 4; m++)
#pragma unroll
    for (int n = 0; n < 4; n++)
#pragma unroll
      for (int r = 0; r < 4; r++) {
        const int row = m0 + wm * 64 + m * 16 + r0 + r;
        const int col = n0 + wn * 64 + n * 16 + cc;
        const size_t idx = (size_t)row * N + col;
        if (EPI == 0) {
          ((float*)outp)[(size_t)ks * M * N + idx] = acc[m][n][r];
        } else {
          float val = acc[m][n][r] + bias[col];
          if (EPI == 3) {
            float u2 = val * (0.7978845608f + 0.0356774081f * val * val);
            u2 = fminf(u2, 10.0f);
            const float e = __expf(2.0f * u2);
            val = val * e / (e + 1.0f);
          }
          ((unsigned short*)outp)[idx] = f2b(val);
        }
      }
}

// ---------------- reduce: dst = sum(parts) ----------------
template <int NP>
__global__ __launch_bounds__(256) void reduce_k(float* __restrict__ dst,
                                                const float* __restrict__ parts,
                                                size_t total) {
  const size_t i = ((size_t)blockIdx.x * 256 + threadIdx.x) * 4;
  if (i >= total) return;
  f32x4 acc = {};
#pragma unroll
  for (int p = 0; p < NP; p++) acc += *(const f32x4*)&parts[(size_t)p * total + i];
  *(f32x4*)&dst[i] = acc;
}

// ---------------- MFMA sparse attention (fused-QKV input, stride QS) ----------------
#define QT 16
#define KT 32
#define NTMAX 6
#define KP 72   // padded K/V tile row (shorts)
#define PP 40   // padded P row (shorts)

__global__ __launch_bounds__(256) void attn_mfma(const unsigned short* __restrict__ qkv,
                                                 unsigned short* __restrict__ outg) {
  __shared__ __align__(16) unsigned short kvs[4][KT * KP];
  __shared__ __align__(16) unsigned short pls[4][QT * PP];
  const int tid = threadIdx.x;
  const int wid = tid >> 6, lane = tid & 63;
  const int qgrp = blockIdx.x & 31;
  const int bh = blockIdx.x >> 5;
  const int h = bh & (HH - 1), b = bh >> 4;
  const size_t baseq = (size_t)b * TT * QS + (size_t)h * HD;
  const size_t baseo = (size_t)b * TT * DD + (size_t)h * HD;
  const int i0 = qgrp * 64 + wid * 16;
  const int g = lane >> 4;
  const int c = lane & 15;

  const int i0b = qgrp * 64 + 48;
  const int ka0b = (i0b > 128) ? ((i0b - 128) & ~31) : 0;
  const int nlb = ((i0b + 16 - ka0b) + 31) >> 5;
  const int neb = (ka0b + 255) >> 8;
  const int ka0 = (i0 > 128) ? ((i0 - 128) & ~31) : 0;
  const int ne = (ka0 + 255) >> 8;

  const s16x8 qf0 = *(const s16x8*)&qkv[baseq + (size_t)(i0 + c) * QS + g * 8];
  const s16x8 qf1 = *(const s16x8*)&qkv[baseq + (size_t)(i0 + c) * QS + 32 + g * 8];

  f32x4 sc[NTMAX][2];
  float smax[4] = {-1e30f, -1e30f, -1e30f, -1e30f};

#pragma unroll
  for (int t = 0; t < NTMAX; t++) {
    if (t > nlb) continue;
    const bool isg = (t == 0);
    if (isg && neb == 0) continue;
    const int kt0 = ka0 + (t - 1) * 32;
#pragma unroll
    for (int it = 0; it < 4; it++) {
      const int row = it * 8 + (lane >> 3);
      const int ch = lane & 7;
      const int j = isg ? ((row < ne) ? row * STRIDE_G : 0) : (kt0 + row);
      *(s16x8*)&kvs[wid][row * KP + ch * 8] =
          *(const s16x8*)&qkv[baseq + DD + (size_t)j * QS + ch * 8];
    }
    __syncthreads();
#pragma unroll
    for (int half = 0; half < 2; half++) {
      const int key = half * 16 + c;
      const bf16x8 kb0 = __builtin_bit_cast(bf16x8, *(const s16x8*)&kvs[wid][key * KP + g * 8]);
      const bf16x8 kb1 = __builtin_bit_cast(bf16x8, *(const s16x8*)&kvs[wid][key * KP + 32 + g * 8]);
      f32x4 a = {};
      a = __builtin_amdgcn_mfma_f32_16x16x32_bf16(__builtin_bit_cast(bf16x8, qf0), kb0, a, 0, 0, 0);
      a = __builtin_amdgcn_mfma_f32_16x16x32_bf16(__builtin_bit_cast(bf16x8, qf1), kb1, a, 0, 0, 0);
#pragma unroll
      for (int r = 0; r < 4; r++) {
        const int i = i0 + g * 4 + r;
        bool ok;
        if (isg) {
          ok = (key < ne);
        } else {
          const int j = kt0 + key;
          ok = (j <= i) && (((i - j) <= LOCAL_W) || ((j & (STRIDE_G - 1)) == 0));
        }
        const float s = ok ? a[r] * 0.125f : -1e30f;
        sc[t][half][r] = s;
        smax[r] = fmaxf(smax[r], s);
      }
    }
    __syncthreads();
  }
#pragma unroll
  for (int r = 0; r < 4; r++)
#pragma unroll
    for (int off = 8; off; off >>= 1)
      smax[r] = fmaxf(smax[r], __shfl_xor(smax[r], off));

  f32x4 o[4] = {};
  float lsum[4] = {0.f, 0.f, 0.f, 0.f};
#pragma unroll
  for (int t = 0; t < NTMAX; t++) {
    if (t > nlb) continue;
    const bool isg = (t == 0);
    if (isg && neb == 0) continue;
    const int kt0 = ka0 + (t - 1) * 32;
#pragma unroll
    for (int it = 0; it < 4; it++) {
      const int row = it * 8 + (lane >> 3);
      const int ch = lane & 7;
      const int j = isg ? ((row < ne) ? row * STRIDE_G : 0) : (kt0 + row);
      *(s16x8*)&kvs[wid][row * KP + ch * 8] =
          *(const s16x8*)&qkv[baseq + 2 * DD + (size_t)j * QS + ch * 8];
    }
#pragma unroll
    for (int half = 0; half < 2; half++)
#pragma unroll
      for (int r = 0; r < 4; r++) {
        const float p = __expf(sc[t][half][r] - smax[r]);
        lsum[r] += p;
        pls[wid][(g * 4 + r) * PP + half * 16 + c] = f2b(p);
      }
    __syncthreads();
    const bf16x8 pa = __builtin_bit_cast(bf16x8, *(const s16x8*)&pls[wid][c * PP + g * 8]);
#pragma unroll
    for (int d0 = 0; d0 < 4; d0++) {
      s16x8 bv;
#pragma unroll
      for (int e = 0; e < 8; e++)
        bv[e] = (short)kvs[wid][(g * 8 + e) * KP + d0 * 16 + c];
      o[d0] = __builtin_amdgcn_mfma_f32_16x16x32_bf16(pa, __builtin_bit_cast(bf16x8, bv), o[d0], 0, 0, 0);
    }
    __syncthreads();
  }
#pragma unroll
  for (int r = 0; r < 4; r++)
#pragma unroll
    for (int off = 8; off; off >>= 1)
      lsum[r] += __shfl_xor(lsum[r], off);
#pragma unroll
  for (int d0 = 0; d0 < 4; d0++)
#pragma unroll
    for (int r = 0; r < 4; r++)
      outg[baseo + (size_t)(i0 + g * 4 + r) * DD + d0 * 16 + c] = f2b(o[d0][r] / lsum[r]);
}

// ---------------- host ----------------
extern "C" void kernel_launch(void* const* d_in, const int* in_sizes, int n_in,
                              void* d_out, int out_size, void* d_ws, size_t ws_size,
                              hipStream_t stream) {
  const int* x = (const int*)d_in[0];
  const float* embed = (const float*)d_in[1];
  const float* pos = (const float*)d_in[2];
  const float* Wq = (const float*)d_in[3];
  const float* bq = (const float*)d_in[4];
  const float* Wk = (const float*)d_in[5];
  const float* bk = (const float*)d_in[6];
  const float* Wv = (const float*)d_in[7];
  const float* bv = (const float*)d_in[8];
  const float* Wo = (const float*)d_in[9];
  const float* bo = (const float*)d_in[10];
  const float* g1 = (const float*)d_in[11];
  const float* be1 = (const float*)d_in[12];
  const float* W1 = (const float*)d_in[13];
  const float* bf1 = (const float*)d_in[14];
  const float* W2 = (const float*)d_in[15];
  const float* bf2 = (const float*)d_in[16];
  const float* g2 = (const float*)d_in[17];
  const float* be2 = (const float*)d_in[18];
  const float* gf = (const float*)d_in[19];
  const float* bef = (const float*)d_in[20];
  const float* Whead = (const float*)d_in[21];

  char* ws = (char*)d_ws;
  size_t off = 0;
  auto alloc = [&](size_t bytes) -> void* {
    void* p = ws + off;
    off += (bytes + 255) & ~(size_t)255;
    return p;
  };
  unsigned short* WqkvT = (unsigned short*)alloc((size_t)2 * QS * DD * 2);
  unsigned short* WoT = (unsigned short*)alloc((size_t)2 * DD * DD * 2);
  unsigned short* W1T = (unsigned short*)alloc((size_t)2 * DD * FF * 2);
  unsigned short* W2T = (unsigned short*)alloc((size_t)2 * DD * FF * 2);
  unsigned short* WheadT = (unsigned short*)alloc((size_t)DD * VV * 2);
  float* bcat = (float*)alloc((size_t)2 * QS * 4);
  float* h = (float*)alloc((size_t)MM * DD * 4);
  unsigned short* hn = (unsigned short*)alloc((size_t)MM * DD * 2);
  unsigned short* qkvb = (unsigned short*)alloc((size_t)MM * QS * 2);   // 24 MB
  unsigned short* attnb = (unsigned short*)alloc((size_t)MM * DD * 2);  // 8 MB
  unsigned short* mid = (unsigned short*)alloc((size_t)MM * FF * 2);    // 32 MB
  float* ffn2p = (float*)qkvb;   // 2 x [MM x DD] f32 overlay (qkvb+attnb dead)
  float* oprojp = (float*)mid;   // 2 x [MM x DD] f32 overlay (mid dead at O-proj)
  float* headp = (float*)mid;    // 4 x [MM x VV] f32 <= mid
  (void)ws_size;

  const dim3 tb(32, 8);
  qkv_t<<<dim3(DD / 32, DD / 32, 6), tb, 0, stream>>>(Wq, Wk, Wv, WqkvT);
  transpose_k<<<dim3(DD / 32, DD / 32, 2), tb, 0, stream>>>(Wo, WoT, DD, DD,
                                                            (size_t)DD * DD, (size_t)DD * DD);
  transpose_k<<<dim3(FF / 32, DD / 32, 2), tb, 0, stream>>>(W1, W1T, DD, FF,
                                                            (size_t)DD * FF, (size_t)DD * FF);
  transpose_k<<<dim3(DD / 32, FF / 32, 2), tb, 0, stream>>>(W2, W2T, FF, DD,
                                                            (size_t)DD * FF, (size_t)DD * FF);
  transpose_k<<<dim3(VV / 32, DD / 32, 1), tb, 0, stream>>>(Whead, WheadT, DD, VV, 0, 0);
  concat_bias<<<24, 256, 0, stream>>>(bq, bk, bv, bcat);

  embed_ln<<<MM, 256, 0, stream>>>(x, embed, pos, g1, be1, h, hn);

  for (int l = 0; l < 2; l++) {
    const size_t wo = (size_t)l * DD * DD;
    const size_t wf = (size_t)l * DD * FF;
    // fused QKV: 128^2, grid 768 = 3 blocks/CU even
    gemm_m<1><<<(QS / 128) * (MM / 128), 256, 0, stream>>>(
        hn, WqkvT + (size_t)l * QS * DD, bcat + l * QS, qkvb,
        MM, QS, DD, QS / 128, MM / 128, 1, DD);
    attn_mfma<<<BB * HH * (TT / 64), 256, 0, stream>>>(qkvb, attnb);
    // O-proj: split-K=2, grid 512 = 2 blocks/CU even
    gemm_m<0><<<2 * (DD / 128) * (MM / 128), 256, 0, stream>>>(
        attnb, WoT + wo, nullptr, oprojp,
        MM, DD, DD, DD / 128, MM / 128, 2, DD / 2);
    ln_red<<<MM, 256, 0, stream>>>(h, oprojp, bo + l * DD, g2 + l * DD, be2 + l * DD, hn);
    // FFN1: GELU, grid 1024 = 4 blocks/CU even
    gemm_m<3><<<(FF / 128) * (MM / 128), 256, 0, stream>>>(
        hn, W1T + wf, bf1 + l * FF, mid,
        MM, FF, DD, FF / 128, MM / 128, 1, DD);
    // FFN2: split-K=2, grid 512
    gemm_m<0><<<2 * (DD / 128) * (MM / 128), 256, 0, stream>>>(
        mid, W2T + wf, nullptr, ffn2p,
        MM, DD, FF, DD / 128, MM / 128, 2, FF / 2);
    if (l == 0)
      ln_red<<<MM, 256, 0, stream>>>(h, ffn2p, bf2, g1 + DD, be1 + DD, hn);
    else
      ln_red<<<MM, 256, 0, stream>>>(h, ffn2p, bf2 + DD, gf, bef, hn);
  }
  // head split-K=4: grid 256 = 8 * (128/4) * (2/2)
  gemm_m<0><<<4 * (VV / 128) * (MM / 128), 256, 0, stream>>>(
      hn, WheadT, nullptr, headp,
      MM, VV, DD, VV / 128, MM / 128, 4, DD / 4);
  reduce_k<4><<<(MM * VV) / 1024, 256, 0, stream>>>(
      (float*)d_out, headp, (size_t)MM * VV);
}

// Round 16
// 428.440 us; speedup vs baseline: 1.0528x; 1.0528x over previous
//
#include <hip/hip_runtime.h>
#include <hip/hip_bf16.h>

// ---------------- problem constants ----------------
#define BB 2
#define TT 2048
#define DD 1024
#define FF 4096
#define VV 256
#define HH 16
#define HD 64
#define MM (BB * TT)      // 4096 rows
#define LOCAL_W 128
#define STRIDE_G 256
#define QS 3072           // fused QKV row stride

typedef short s16x8 __attribute__((ext_vector_type(8)));
typedef __bf16 bf16x8 __attribute__((ext_vector_type(8)));
typedef float f32x4 __attribute__((ext_vector_type(4)));

#define WAITVM(N) asm volatile("s_waitcnt vmcnt(" #N ")" ::: "memory")
#define CFENCE asm volatile("" ::: "memory")

__device__ __forceinline__ float b2f(unsigned short u) {
  return __builtin_bit_cast(float, (unsigned int)u << 16);
}
__device__ __forceinline__ unsigned short f2b(float f) {
  __hip_bfloat16 h = __float2bfloat16(f);  // RNE
  return __builtin_bit_cast(unsigned short, h);
}
// async global->LDS, 16B per lane; LDS dest = wave-uniform base + lane*16
__device__ __forceinline__ void gl_lds16(const unsigned short* g, unsigned short* l) {
  __builtin_amdgcn_global_load_lds(
      (const __attribute__((address_space(1))) void*)g,
      (__attribute__((address_space(3))) void*)l, 16, 0, 0);
}
__device__ __forceinline__ bf16x8 ldsr(const unsigned short* p) {
  return __builtin_bit_cast(bf16x8, *(const s16x8*)p);
}

// ------- batched weight transpose f32[K][N] -> bf16[N][K], z = batch -------
__global__ __launch_bounds__(256) void transpose_k(const float* __restrict__ W,
                                                   unsigned short* __restrict__ WT,
                                                   int K, int N,
                                                   size_t sstride, size_t dstride) {
  __shared__ float t[32][33];
  const int z = blockIdx.z;
  W += (size_t)z * sstride;
  WT += (size_t)z * dstride;
  const int n0 = blockIdx.x * 32, k0 = blockIdx.y * 32;
  const int tx = threadIdx.x, ty = threadIdx.y;  // (32, 8)
  for (int r = ty; r < 32; r += 8) t[r][tx] = W[(size_t)(k0 + r) * N + n0 + tx];
  __syncthreads();
  for (int r = ty; r < 32; r += 8)
    WT[(size_t)(n0 + r) * K + k0 + tx] = f2b(t[tx][r]);
}

// ------- QKV transpose: z in 0..5 = (layer, which) -> WqkvT[l][3DD][DD] ----
__global__ __launch_bounds__(256) void qkv_t(const float* __restrict__ Wq,
                                             const float* __restrict__ Wk,
                                             const float* __restrict__ Wv,
                                             unsigned short* __restrict__ WT) {
  __shared__ float t[32][33];
  const int z = blockIdx.z;
  const int l = z / 3, which = z % 3;
  const float* W = (which == 0 ? Wq : which == 1 ? Wk : Wv) + (size_t)l * DD * DD;
  unsigned short* D = WT + ((size_t)l * QS + which * DD) * DD;
  const int n0 = blockIdx.x * 32, k0 = blockIdx.y * 32;
  const int tx = threadIdx.x, ty = threadIdx.y;
  for (int r = ty; r < 32; r += 8) t[r][tx] = W[(size_t)(k0 + r) * DD + n0 + tx];
  __syncthreads();
  for (int r = ty; r < 32; r += 8)
    D[(size_t)(n0 + r) * DD + k0 + tx] = f2b(t[tx][r]);
}

// ---------------- concat QKV bias: bcat[l][3072] ----------------
__global__ __launch_bounds__(256) void concat_bias(const float* __restrict__ bq,
                                                   const float* __restrict__ bk,
                                                   const float* __restrict__ bv,
                                                   float* __restrict__ bcat) {
  const int i = blockIdx.x * 256 + threadIdx.x;  // 6144 total
  const int l = i / QS, j = i - l * QS;
  float v;
  if (j < DD) v = bq[l * DD + j];
  else if (j < 2 * DD) v = bk[l * DD + j - DD];
  else v = bv[l * DD + j - 2 * DD];
  bcat[i] = v;
}

// ------- fused embedding + positional + layer-0 LN1 (h + hn out) -----------
__global__ __launch_bounds__(256) void embed_ln(const int* __restrict__ x,
                                                const float* __restrict__ emb,
                                                const float* __restrict__ pos,
                                                const float* __restrict__ g,
                                                const float* __restrict__ be,
                                                float* __restrict__ h,
                                                unsigned short* __restrict__ out) {
  const int row = blockIdx.x;
  const int tid = threadIdx.x;
  const int tok = x[row];
  const int t = row & (TT - 1);
  f32x4 v = *(const f32x4*)&emb[(size_t)tok * DD + tid * 4];
  v += *(const f32x4*)&pos[(size_t)t * DD + tid * 4];
  *(f32x4*)&h[(size_t)row * DD + tid * 4] = v;
  float s = v[0] + v[1] + v[2] + v[3];
  float sq = v[0] * v[0] + v[1] * v[1] + v[2] * v[2] + v[3] * v[3];
#pragma unroll
  for (int off = 32; off; off >>= 1) {
    s += __shfl_xor(s, off);
    sq += __shfl_xor(sq, off);
  }
  __shared__ float ss[4], ssq[4];
  const int w = tid >> 6, lane = tid & 63;
  if (lane == 0) { ss[w] = s; ssq[w] = sq; }
  __syncthreads();
  s = ss[0] + ss[1] + ss[2] + ss[3];
  sq = ssq[0] + ssq[1] + ssq[2] + ssq[3];
  const float mean = s * (1.0f / DD);
  const float var = sq * (1.0f / DD) - mean * mean;
  const float rstd = rsqrtf(var + 1e-5f);
  const float4 gv = *(const float4*)&g[tid * 4];
  const float4 bv = *(const float4*)&be[tid * 4];
  ushort4 o;
  o.x = f2b((v[0] - mean) * rstd * gv.x + bv.x);
  o.y = f2b((v[1] - mean) * rstd * gv.y + bv.y);
  o.z = f2b((v[2] - mean) * rstd * gv.z + bv.z);
  o.w = f2b((v[3] - mean) * rstd * gv.w + bv.w);
  *(ushort4*)&out[(size_t)row * DD + tid * 4] = o;
}

// ---- fused split-K reduce + residual + LayerNorm ----
__global__ __launch_bounds__(256) void ln_red(float* __restrict__ hio,
                                              const float* __restrict__ parts,
                                              const float* __restrict__ bias,
                                              const float* __restrict__ g,
                                              const float* __restrict__ be,
                                              unsigned short* __restrict__ out) {
  const int row = blockIdx.x;
  const int tid = threadIdx.x;
  const size_t base = (size_t)row * DD + tid * 4;
  f32x4 v = *(const f32x4*)&hio[base];
  v += *(const f32x4*)&bias[tid * 4];
  v += *(const f32x4*)&parts[base];
  v += *(const f32x4*)&parts[(size_t)MM * DD + base];
  *(f32x4*)&hio[base] = v;
  float s = v[0] + v[1] + v[2] + v[3];
  float sq = v[0] * v[0] + v[1] * v[1] + v[2] * v[2] + v[3] * v[3];
#pragma unroll
  for (int off = 32; off; off >>= 1) {
    s += __shfl_xor(s, off);
    sq += __shfl_xor(sq, off);
  }
  __shared__ float ss[4], ssq[4];
  const int w = tid >> 6, lane = tid & 63;
  if (lane == 0) { ss[w] = s; ssq[w] = sq; }
  __syncthreads();
  s = ss[0] + ss[1] + ss[2] + ss[3];
  sq = ssq[0] + ssq[1] + ssq[2] + ssq[3];
  const float mean = s * (1.0f / DD);
  const float var = sq * (1.0f / DD) - mean * mean;
  const float rstd = rsqrtf(var + 1e-5f);
  const float4 gv = *(const float4*)&g[tid * 4];
  const float4 bv = *(const float4*)&be[tid * 4];
  ushort4 o;
  o.x = f2b((v[0] - mean) * rstd * gv.x + bv.x);
  o.y = f2b((v[1] - mean) * rstd * gv.y + bv.y);
  o.z = f2b((v[2] - mean) * rstd * gv.z + bv.z);
  o.w = f2b((v[3] - mean) * rstd * gv.w + bv.w);
  *(ushort4*)&out[(size_t)row * DD + tid * 4] = o;
}

// ------- 256x128 derived-waits GEMM, 3-slot ring, 64x64 wave tiles ---------
// 8 waves as 4M x 2N -> wave tile 64 rows x 64 cols: per slot 8 ds_read_b128
// feed 16 MFMA (0.5 KB/MFMA). 2-D XCD region map (g_m=4 x g_n=2): XCD x owns
// m-region (x>>1) x n-region (x&1); per-XCD L2 working set ~6 MB. Slot ring
// c0/c1/c2 (73.7 KB -> 2 blocks/CU), WAITVM(3) counted publishes.
// EPI: 0 = f32 split-K partial @ out + ks*M*N; 1 = bf16+bias; 3 = bf16 GELU.
template <int EPI>
__global__ __launch_bounds__(512, 4) void gemm_dw3(const unsigned short* __restrict__ A,
                                                   const unsigned short* __restrict__ BT,
                                                   const float* __restrict__ bias,
                                                   void* __restrict__ outp,
                                                   int M, int N, int K,
                                                   int nbx, int nby, int ksplit,
                                                   int ksub) {
  __shared__ __align__(16) unsigned short lds[36864];  // 3 x 12288 shorts
  const int tid = threadIdx.x;
  const int lane = tid & 63;
  const int w = tid >> 6;
  // 2-D XCD region mapping (g_m=4, g_n=2), m-inner within region
  const int o = blockIdx.x;
  const int xcd = o & 7;
  const int j = o >> 3;
  const int m_per = (nby * ksplit) >> 2;  // nby_eff / g_m
  const int n_per = nbx >> 1;             // nbx / g_n
  const int m_loc = j % m_per, n_loc = j / m_per;
  const int m_idx = (xcd >> 1) * m_per + m_loc;
  const int n_idx = (xcd & 1) * n_per + n_loc;
  const int ks = m_idx / nby;
  const int mp = m_idx - ks * nby;
  const int n0 = n_idx * 128;
  const int m0 = mp * 256;
  const int kb = ks * ksub;
  const int wm = w >> 1, wn = w & 1;  // wave tile: 64 rows x 64 cols
  f32x4 acc[4][4] = {};

  const unsigned short* aSrc[2];
  const unsigned short* bSrc;
  int dstA[2], dstB;
#pragma unroll
  for (int i = 0; i < 2; i++) {
    const int s = tid + (i << 9);
    const int row = s >> 2, sc = s & 3;
    const int l = sc ^ ((row >> 1) & 3);
    aSrc[i] = &A[(size_t)(m0 + row) * K + kb + l * 8];
    dstA[i] = s * 8;
  }
  {
    const int row = tid >> 2, sc = tid & 3;
    const int l = sc ^ ((row >> 1) & 3);
    bSrc = &BT[(size_t)(n0 + row) * K + kb + l * 8];
    dstB = 8192 + tid * 8;
  }
  auto STAGE = [&](int u, int base) {
    const int kt = u << 5;
    gl_lds16(aSrc[0] + kt, &lds[base + dstA[0]]);
    gl_lds16(aSrc[1] + kt, &lds[base + dstA[1]]);
    gl_lds16(bSrc + kt, &lds[base + dstB]);
  };

  const int rA = lane & 15, cr = lane >> 4;
  const int rowA0 = wm * 64 + rA;
  const int rowB0 = wn * 64 + rA;
  const int aAddr0 = rowA0 * 32 + ((cr ^ ((rowA0 >> 1) & 3)) << 3);
  const int bAddr0 = 8192 + rowB0 * 32 + ((cr ^ ((rowB0 >> 1) & 3)) << 3);

  const int NS = ksub >> 5;  // slots (>= 16)
  int c0 = 0, c1 = 12288, c2 = 24576;
  STAGE(0, c0);
  STAGE(1, c1);

  for (int u = 0; u < NS; ++u) {
    if (u + 1 < NS) { WAITVM(3); } else { WAITVM(0); }
    __builtin_amdgcn_s_barrier();
    CFENCE;
    if (u + 2 < NS) STAGE(u + 2, c2);
    bf16x8 bfr[4], af[4];
#pragma unroll
    for (int n = 0; n < 4; n++) bfr[n] = ldsr(&lds[c0 + bAddr0 + n * 512]);
#pragma unroll
    for (int i = 0; i < 4; i++) af[i] = ldsr(&lds[c0 + aAddr0 + i * 512]);
    __builtin_amdgcn_s_setprio(1);
#pragma unroll
    for (int i = 0; i < 4; i++)
#pragma unroll
      for (int n = 0; n < 4; n++)
        acc[i][n] = __builtin_amdgcn_mfma_f32_16x16x32_bf16(af[i], bfr[n], acc[i][n], 0, 0, 0);
    __builtin_amdgcn_s_setprio(0);
    const int t = c0; c0 = c1; c1 = c2; c2 = t;  // rotate ring
  }

  const int r0 = (lane >> 4) * 4;
  const int cc = lane & 15;
#pragma unroll
  for (int m = 0; m < 4; m++)
#pragma unroll
    for (int n = 0; n < 4; n++)
#pragma unroll
      for (int r = 0; r < 4; r++) {
        const int row = m0 + wm * 64 + m * 16 + r0 + r;
        const int col = n0 + wn * 64 + n * 16 + cc;
        const size_t idx = (size_t)row * N + col;
        if (EPI == 0) {
          ((float*)outp)[(size_t)ks * M * N + idx] = acc[m][n][r];
        } else {
          float val = acc[m][n][r] + bias[col];
          if (EPI == 3) {
            float u2 = val * (0.7978845608f + 0.0356774081f * val * val);
            u2 = fminf(u2, 10.0f);
            const float e = __expf(2.0f * u2);
            val = val * e / (e + 1.0f);
          }
          ((unsigned short*)outp)[idx] = f2b(val);
        }
      }
}

// ---------------- pipelined 128^2 bf16 MFMA GEMM (head only) ----------------
__global__ __launch_bounds__(512, 2) void gemm_p(const unsigned short* __restrict__ A,
                                                 const unsigned short* __restrict__ BT,
                                                 float* __restrict__ outp,
                                                 int M, int N, int K, int nbx, int nwg2,
                                                 int ksub) {
  constexpr int BM = 128;
  __shared__ __align__(16) unsigned short lds[4][BM * 64];
  const int tid = threadIdx.x;
  const int lane = tid & 63;
  const int w = tid >> 6;
  const int nwg = gridDim.x;
  const int orig = blockIdx.x;
  const int wg = (orig & 7) * (nwg >> 3) + (orig >> 3);
  const int ks = wg / nwg2;
  const int rem = wg - ks * nwg2;
  const int n0 = (rem % nbx) * BM;
  const int m0 = (rem / nbx) * BM;
  const int kb = ks * ksub;
  const int wm = w >> 2, wn = w & 3;
  f32x4 acc[4][2] = {};

  auto STAGE = [&](int t) {
    const int b = t & 3;
    const int kt = kb + (t << 5);
    const int s = tid;
    const int row = s >> 2, sc = s & 3;
    const int c = sc ^ ((row >> 1) & 3);
    gl_lds16(&A[(size_t)(m0 + row) * K + kt + c * 8], &lds[b][s * 8]);
    gl_lds16(&BT[(size_t)(n0 + row) * K + kt + c * 8], &lds[b][BM * 32 + s * 8]);
  };

  const int NT = ksub >> 5;
  STAGE(0); STAGE(1); STAGE(2);

  for (int t = 0; t < NT; ++t) {
    const int ahead = NT - 1 - t;
    if (ahead >= 2) WAITVM(4); else if (ahead == 1) WAITVM(2); else WAITVM(0);
    __builtin_amdgcn_s_barrier();
    CFENCE;
    if (t + 3 < NT) STAGE(t + 3);
    const int b = t & 3;
    const int rA = lane & 15, cr = lane >> 4;
    bf16x8 af[4], bfr[2];
#pragma unroll
    for (int m = 0; m < 4; m++) {
      const int row = wm * 64 + m * 16 + rA;
      af[m] = ldsr(&lds[b][row * 32 + ((cr ^ ((row >> 1) & 3)) << 3)]);
    }
#pragma unroll
    for (int n = 0; n < 2; n++) {
      const int row = wn * 32 + n * 16 + rA;
      bfr[n] = ldsr(&lds[b][BM * 32 + row * 32 + ((cr ^ ((row >> 1) & 3)) << 3)]);
    }
    __builtin_amdgcn_s_setprio(1);
#pragma unroll
    for (int m = 0; m < 4; m++)
#pragma unroll
      for (int n = 0; n < 2; n++)
        acc[m][n] = __builtin_amdgcn_mfma_f32_16x16x32_bf16(af[m], bfr[n], acc[m][n], 0, 0, 0);
    __builtin_amdgcn_s_setprio(0);
  }

  const int r0 = (lane >> 4) * 4;
  const int cc = lane & 15;
  float* pout = outp + (size_t)ks * M * N;
#pragma unroll
  for (int m = 0; m < 4; m++)
#pragma unroll
    for (int n = 0; n < 2; n++)
#pragma unroll
      for (int r = 0; r < 4; r++) {
        const int row = m0 + wm * 64 + m * 16 + r0 + r;
        const int col = n0 + wn * 32 + n * 16 + cc;
        pout[(size_t)row * N + col] = acc[m][n][r];
      }
}

// ---------------- reduce: dst = sum(parts) ----------------
template <int NP>
__global__ __launch_bounds__(256) void reduce_k(float* __restrict__ dst,
                                                const float* __restrict__ parts,
                                                size_t total) {
  const size_t i = ((size_t)blockIdx.x * 256 + threadIdx.x) * 4;
  if (i >= total) return;
  f32x4 acc = {};
#pragma unroll
  for (int p = 0; p < NP; p++) acc += *(const f32x4*)&parts[(size_t)p * total + i];
  *(f32x4*)&dst[i] = acc;
}

// ---------------- MFMA sparse attention (fused-QKV input, stride QS) ----------------
#define QT 16
#define KT 32
#define NTMAX 6
#define KP 72   // padded K/V tile row (shorts)
#define PP 40   // padded P row (shorts)

__global__ __launch_bounds__(256) void attn_mfma(const unsigned short* __restrict__ qkv,
                                                 unsigned short* __restrict__ outg) {
  __shared__ __align__(16) unsigned short kvs[4][KT * KP];
  __shared__ __align__(16) unsigned short pls[4][QT * PP];
  const int tid = threadIdx.x;
  const int wid = tid >> 6, lane = tid & 63;
  const int qgrp = blockIdx.x & 31;
  const int bh = blockIdx.x >> 5;
  const int h = bh & (HH - 1), b = bh >> 4;
  const size_t baseq = (size_t)b * TT * QS + (size_t)h * HD;
  const size_t baseo = (size_t)b * TT * DD + (size_t)h * HD;
  const int i0 = qgrp * 64 + wid * 16;
  const int g = lane >> 4;
  const int c = lane & 15;

  const int i0b = qgrp * 64 + 48;
  const int ka0b = (i0b > 128) ? ((i0b - 128) & ~31) : 0;
  const int nlb = ((i0b + 16 - ka0b) + 31) >> 5;
  const int neb = (ka0b + 255) >> 8;
  const int ka0 = (i0 > 128) ? ((i0 - 128) & ~31) : 0;
  const int ne = (ka0 + 255) >> 8;

  const s16x8 qf0 = *(const s16x8*)&qkv[baseq + (size_t)(i0 + c) * QS + g * 8];
  const s16x8 qf1 = *(const s16x8*)&qkv[baseq + (size_t)(i0 + c) * QS + 32 + g * 8];

  f32x4 sc[NTMAX][2];
  float smax[4] = {-1e30f, -1e30f, -1e30f, -1e30f};

#pragma unroll
  for (int t = 0; t < NTMAX; t++) {
    if (t > nlb) continue;
    const bool isg = (t == 0);
    if (isg && neb == 0) continue;
    const int kt0 = ka0 + (t - 1) * 32;
#pragma unroll
    for (int it = 0; it < 4; it++) {
      const int row = it * 8 + (lane >> 3);
      const int ch = lane & 7;
      const int j = isg ? ((row < ne) ? row * STRIDE_G : 0) : (kt0 + row);
      *(s16x8*)&kvs[wid][row * KP + ch * 8] =
          *(const s16x8*)&qkv[baseq + DD + (size_t)j * QS + ch * 8];
    }
    __syncthreads();
#pragma unroll
    for (int half = 0; half < 2; half++) {
      const int key = half * 16 + c;
      const bf16x8 kb0 = __builtin_bit_cast(bf16x8, *(const s16x8*)&kvs[wid][key * KP + g * 8]);
      const bf16x8 kb1 = __builtin_bit_cast(bf16x8, *(const s16x8*)&kvs[wid][key * KP + 32 + g * 8]);
      f32x4 a = {};
      a = __builtin_amdgcn_mfma_f32_16x16x32_bf16(__builtin_bit_cast(bf16x8, qf0), kb0, a, 0, 0, 0);
      a = __builtin_amdgcn_mfma_f32_16x16x32_bf16(__builtin_bit_cast(bf16x8, qf1), kb1, a, 0, 0, 0);
#pragma unroll
      for (int r = 0; r < 4; r++) {
        const int i = i0 + g * 4 + r;
        bool ok;
        if (isg) {
          ok = (key < ne);
        } else {
          const int j = kt0 + key;
          ok = (j <= i) && (((i - j) <= LOCAL_W) || ((j & (STRIDE_G - 1)) == 0));
        }
        const float s = ok ? a[r] * 0.125f : -1e30f;
        sc[t][half][r] = s;
        smax[r] = fmaxf(smax[r], s);
      }
    }
    __syncthreads();
  }
#pragma unroll
  for (int r = 0; r < 4; r++)
#pragma unroll
    for (int off = 8; off; off >>= 1)
      smax[r] = fmaxf(smax[r], __shfl_xor(smax[r], off));

  f32x4 o[4] = {};
  float lsum[4] = {0.f, 0.f, 0.f, 0.f};
#pragma unroll
  for (int t = 0; t < NTMAX; t++) {
    if (t > nlb) continue;
    const bool isg = (t == 0);
    if (isg && neb == 0) continue;
    const int kt0 = ka0 + (t - 1) * 32;
#pragma unroll
    for (int it = 0; it < 4; it++) {
      const int row = it * 8 + (lane >> 3);
      const int ch = lane & 7;
      const int j = isg ? ((row < ne) ? row * STRIDE_G : 0) : (kt0 + row);
      *(s16x8*)&kvs[wid][row * KP + ch * 8] =
          *(const s16x8*)&qkv[baseq + 2 * DD + (size_t)j * QS + ch * 8];
    }
#pragma unroll
    for (int half = 0; half < 2; half++)
#pragma unroll
      for (int r = 0; r < 4; r++) {
        const float p = __expf(sc[t][half][r] - smax[r]);
        lsum[r] += p;
        pls[wid][(g * 4 + r) * PP + half * 16 + c] = f2b(p);
      }
    __syncthreads();
    const bf16x8 pa = __builtin_bit_cast(bf16x8, *(const s16x8*)&pls[wid][c * PP + g * 8]);
#pragma unroll
    for (int d0 = 0; d0 < 4; d0++) {
      s16x8 bv;
#pragma unroll
      for (int e = 0; e < 8; e++)
        bv[e] = (short)kvs[wid][(g * 8 + e) * KP + d0 * 16 + c];
      o[d0] = __builtin_amdgcn_mfma_f32_16x16x32_bf16(pa, __builtin_bit_cast(bf16x8, bv), o[d0], 0, 0, 0);
    }
    __syncthreads();
  }
#pragma unroll
  for (int r = 0; r < 4; r++)
#pragma unroll
    for (int off = 8; off; off >>= 1)
      lsum[r] += __shfl_xor(lsum[r], off);
#pragma unroll
  for (int d0 = 0; d0 < 4; d0++)
#pragma unroll
    for (int r = 0; r < 4; r++)
      outg[baseo + (size_t)(i0 + g * 4 + r) * DD + d0 * 16 + c] = f2b(o[d0][r] / lsum[r]);
}

// ---------------- host ----------------
extern "C" void kernel_launch(void* const* d_in, const int* in_sizes, int n_in,
                              void* d_out, int out_size, void* d_ws, size_t ws_size,
                              hipStream_t stream) {
  const int* x = (const int*)d_in[0];
  const float* embed = (const float*)d_in[1];
  const float* pos = (const float*)d_in[2];
  const float* Wq = (const float*)d_in[3];
  const float* bq = (const float*)d_in[4];
  const float* Wk = (const float*)d_in[5];
  const float* bk = (const float*)d_in[6];
  const float* Wv = (const float*)d_in[7];
  const float* bv = (const float*)d_in[8];
  const float* Wo = (const float*)d_in[9];
  const float* bo = (const float*)d_in[10];
  const float* g1 = (const float*)d_in[11];
  const float* be1 = (const float*)d_in[12];
  const float* W1 = (const float*)d_in[13];
  const float* bf1 = (const float*)d_in[14];
  const float* W2 = (const float*)d_in[15];
  const float* bf2 = (const float*)d_in[16];
  const float* g2 = (const float*)d_in[17];
  const float* be2 = (const float*)d_in[18];
  const float* gf = (const float*)d_in[19];
  const float* bef = (const float*)d_in[20];
  const float* Whead = (const float*)d_in[21];

  char* ws = (char*)d_ws;
  size_t off = 0;
  auto alloc = [&](size_t bytes) -> void* {
    void* p = ws + off;
    off += (bytes + 255) & ~(size_t)255;
    return p;
  };
  unsigned short* WqkvT = (unsigned short*)alloc((size_t)2 * QS * DD * 2);
  unsigned short* WoT = (unsigned short*)alloc((size_t)2 * DD * DD * 2);
  unsigned short* W1T = (unsigned short*)alloc((size_t)2 * DD * FF * 2);
  unsigned short* W2T = (unsigned short*)alloc((size_t)2 * DD * FF * 2);
  unsigned short* WheadT = (unsigned short*)alloc((size_t)DD * VV * 2);
  float* bcat = (float*)alloc((size_t)2 * QS * 4);
  float* h = (float*)alloc((size_t)MM * DD * 4);
  unsigned short* hn = (unsigned short*)alloc((size_t)MM * DD * 2);
  unsigned short* qkvb = (unsigned short*)alloc((size_t)MM * QS * 2);   // 24 MB
  unsigned short* attnb = (unsigned short*)alloc((size_t)MM * DD * 2);  // 8 MB
  unsigned short* mid = (unsigned short*)alloc((size_t)MM * FF * 2);    // 32 MB
  float* ffn2p = (float*)qkvb;   // 2 x [MM x DD] f32 overlay (qkvb+attnb dead)
  float* oprojp = (float*)mid;   // 2 x [MM x DD] f32 overlay (mid dead at O-proj)
  float* headp = (float*)mid;    // 4 x [MM x VV] f32 <= mid
  (void)ws_size;

  const dim3 tb(32, 8);
  qkv_t<<<dim3(DD / 32, DD / 32, 6), tb, 0, stream>>>(Wq, Wk, Wv, WqkvT);
  transpose_k<<<dim3(DD / 32, DD / 32, 2), tb, 0, stream>>>(Wo, WoT, DD, DD,
                                                            (size_t)DD * DD, (size_t)DD * DD);
  transpose_k<<<dim3(FF / 32, DD / 32, 2), tb, 0, stream>>>(W1, W1T, DD, FF,
                                                            (size_t)DD * FF, (size_t)DD * FF);
  transpose_k<<<dim3(DD / 32, FF / 32, 2), tb, 0, stream>>>(W2, W2T, FF, DD,
                                                            (size_t)DD * FF, (size_t)DD * FF);
  transpose_k<<<dim3(VV / 32, DD / 32, 1), tb, 0, stream>>>(Whead, WheadT, DD, VV, 0, 0);
  concat_bias<<<24, 256, 0, stream>>>(bq, bk, bv, bcat);

  embed_ln<<<MM, 256, 0, stream>>>(x, embed, pos, g1, be1, h, hn);

  for (int l = 0; l < 2; l++) {
    const size_t wo = (size_t)l * DD * DD;
    const size_t wf = (size_t)l * DD * FF;
    // fused QKV: grid 384 = 8 * (16/4) * (24/2)
    gemm_dw3<1><<<(QS / 128) * (MM / 256), 512, 0, stream>>>(
        hn, WqkvT + (size_t)l * QS * DD, bcat + l * QS, qkvb,
        MM, QS, DD, QS / 128, MM / 256, 1, DD);
    attn_mfma<<<BB * HH * (TT / 64), 256, 0, stream>>>(qkvb, attnb);
    // O-proj: split-K=2, grid 256 = 8 * (32/4) * (8/2)
    gemm_dw3<0><<<2 * (DD / 128) * (MM / 256), 512, 0, stream>>>(
        attnb, WoT + wo, nullptr, oprojp,
        MM, DD, DD, DD / 128, MM / 256, 2, DD / 2);
    ln_red<<<MM, 256, 0, stream>>>(h, oprojp, bo + l * DD, g2 + l * DD, be2 + l * DD, hn);
    // FFN1: GELU, grid 512 = 8 * (16/4) * (32/2)
    gemm_dw3<3><<<(FF / 128) * (MM / 256), 512, 0, stream>>>(
        hn, W1T + wf, bf1 + l * FF, mid,
        MM, FF, DD, FF / 128, MM / 256, 1, DD);
    // FFN2: split-K=2, grid 256
    gemm_dw3<0><<<2 * (DD / 128) * (MM / 256), 512, 0, stream>>>(
        mid, W2T + wf, nullptr, ffn2p,
        MM, DD, FF, DD / 128, MM / 256, 2, FF / 2);
    if (l == 0)
      ln_red<<<MM, 256, 0, stream>>>(h, ffn2p, bf2, g1 + DD, be1 + DD, hn);
    else
      ln_red<<<MM, 256, 0, stream>>>(h, ffn2p, bf2 + DD, gf, bef, hn);
  }
  // head split-K=4 -> partials -> d_out (f32)
  gemm_p<<<4 * (VV / 128) * (MM / 128), 512, 0, stream>>>(
      hn, WheadT, headp, MM, VV, DD, VV / 128, (VV / 128) * (MM / 128), DD / 4);
  reduce_k<4><<<(MM * VV) / 1024, 256, 0, stream>>>(
      (float*)d_out, headp, (size_t)MM * VV);
}

// Round 17
// 417.231 us; speedup vs baseline: 1.0811x; 1.0269x over previous
//
#include <hip/hip_runtime.h>
#include <hip/hip_bf16.h>

// ---------------- problem constants ----------------
#define BB 2
#define TT 2048
#define DD 1024
#define FF 4096
#define VV 256
#define HH 16
#define HD 64
#define MM (BB * TT)      // 4096 rows
#define LOCAL_W 128
#define STRIDE_G 256
#define QS 3072           // fused QKV row stride

typedef short s16x8 __attribute__((ext_vector_type(8)));
typedef __bf16 bf16x8 __attribute__((ext_vector_type(8)));
typedef float f32x4 __attribute__((ext_vector_type(4)));

#define WAITVM(N) asm volatile("s_waitcnt vmcnt(" #N ")" ::: "memory")
#define CFENCE asm volatile("" ::: "memory")

__device__ __forceinline__ float b2f(unsigned short u) {
  return __builtin_bit_cast(float, (unsigned int)u << 16);
}
__device__ __forceinline__ unsigned short f2b(float f) {
  __hip_bfloat16 h = __float2bfloat16(f);  // RNE
  return __builtin_bit_cast(unsigned short, h);
}
// async global->LDS, 16B per lane; LDS dest = wave-uniform base + lane*16
__device__ __forceinline__ void gl_lds16(const unsigned short* g, unsigned short* l) {
  __builtin_amdgcn_global_load_lds(
      (const __attribute__((address_space(1))) void*)g,
      (__attribute__((address_space(3))) void*)l, 16, 0, 0);
}
__device__ __forceinline__ bf16x8 ldsr(const unsigned short* p) {
  return __builtin_bit_cast(bf16x8, *(const s16x8*)p);
}

// ------- batched weight transpose f32[K][N] -> bf16[N][K], z = batch -------
__global__ __launch_bounds__(256) void transpose_k(const float* __restrict__ W,
                                                   unsigned short* __restrict__ WT,
                                                   int K, int N,
                                                   size_t sstride, size_t dstride) {
  __shared__ float t[32][33];
  const int z = blockIdx.z;
  W += (size_t)z * sstride;
  WT += (size_t)z * dstride;
  const int n0 = blockIdx.x * 32, k0 = blockIdx.y * 32;
  const int tx = threadIdx.x, ty = threadIdx.y;  // (32, 8)
  for (int r = ty; r < 32; r += 8) t[r][tx] = W[(size_t)(k0 + r) * N + n0 + tx];
  __syncthreads();
  for (int r = ty; r < 32; r += 8)
    WT[(size_t)(n0 + r) * K + k0 + tx] = f2b(t[tx][r]);
}

// ------- QKV transpose: z in 0..5 = (layer, which) -> WqkvT[l][3DD][DD] ----
__global__ __launch_bounds__(256) void qkv_t(const float* __restrict__ Wq,
                                             const float* __restrict__ Wk,
                                             const float* __restrict__ Wv,
                                             unsigned short* __restrict__ WT) {
  __shared__ float t[32][33];
  const int z = blockIdx.z;
  const int l = z / 3, which = z % 3;
  const float* W = (which == 0 ? Wq : which == 1 ? Wk : Wv) + (size_t)l * DD * DD;
  unsigned short* D = WT + ((size_t)l * QS + which * DD) * DD;
  const int n0 = blockIdx.x * 32, k0 = blockIdx.y * 32;
  const int tx = threadIdx.x, ty = threadIdx.y;
  for (int r = ty; r < 32; r += 8) t[r][tx] = W[(size_t)(k0 + r) * DD + n0 + tx];
  __syncthreads();
  for (int r = ty; r < 32; r += 8)
    D[(size_t)(n0 + r) * DD + k0 + tx] = f2b(t[tx][r]);
}

// ---------------- concat QKV bias: bcat[l][3072] ----------------
__global__ __launch_bounds__(256) void concat_bias(const float* __restrict__ bq,
                                                   const float* __restrict__ bk,
                                                   const float* __restrict__ bv,
                                                   float* __restrict__ bcat) {
  const int i = blockIdx.x * 256 + threadIdx.x;  // 6144 total
  const int l = i / QS, j = i - l * QS;
  float v;
  if (j < DD) v = bq[l * DD + j];
  else if (j < 2 * DD) v = bk[l * DD + j - DD];
  else v = bv[l * DD + j - 2 * DD];
  bcat[i] = v;
}

// ------- fused embedding + positional + layer-0 LN1 (h + hn out) -----------
__global__ __launch_bounds__(256) void embed_ln(const int* __restrict__ x,
                                                const float* __restrict__ emb,
                                                const float* __restrict__ pos,
                                                const float* __restrict__ g,
                                                const float* __restrict__ be,
                                                float* __restrict__ h,
                                                unsigned short* __restrict__ out) {
  const int row = blockIdx.x;
  const int tid = threadIdx.x;
  const int tok = x[row];
  const int t = row & (TT - 1);
  f32x4 v = *(const f32x4*)&emb[(size_t)tok * DD + tid * 4];
  v += *(const f32x4*)&pos[(size_t)t * DD + tid * 4];
  *(f32x4*)&h[(size_t)row * DD + tid * 4] = v;
  float s = v[0] + v[1] + v[2] + v[3];
  float sq = v[0] * v[0] + v[1] * v[1] + v[2] * v[2] + v[3] * v[3];
#pragma unroll
  for (int off = 32; off; off >>= 1) {
    s += __shfl_xor(s, off);
    sq += __shfl_xor(sq, off);
  }
  __shared__ float ss[4], ssq[4];
  const int w = tid >> 6, lane = tid & 63;
  if (lane == 0) { ss[w] = s; ssq[w] = sq; }
  __syncthreads();
  s = ss[0] + ss[1] + ss[2] + ss[3];
  sq = ssq[0] + ssq[1] + ssq[2] + ssq[3];
  const float mean = s * (1.0f / DD);
  const float var = sq * (1.0f / DD) - mean * mean;
  const float rstd = rsqrtf(var + 1e-5f);
  const float4 gv = *(const float4*)&g[tid * 4];
  const float4 bv = *(const float4*)&be[tid * 4];
  ushort4 o;
  o.x = f2b((v[0] - mean) * rstd * gv.x + bv.x);
  o.y = f2b((v[1] - mean) * rstd * gv.y + bv.y);
  o.z = f2b((v[2] - mean) * rstd * gv.z + bv.z);
  o.w = f2b((v[3] - mean) * rstd * gv.w + bv.w);
  *(ushort4*)&out[(size_t)row * DD + tid * 4] = o;
}

// ---- fused split-K reduce (bf16 partials) + residual + LayerNorm ----
__global__ __launch_bounds__(256) void ln_red(float* __restrict__ hio,
                                              const unsigned short* __restrict__ parts,
                                              const float* __restrict__ bias,
                                              const float* __restrict__ g,
                                              const float* __restrict__ be,
                                              unsigned short* __restrict__ out) {
  const int row = blockIdx.x;
  const int tid = threadIdx.x;
  const size_t base = (size_t)row * DD + tid * 4;
  f32x4 v = *(const f32x4*)&hio[base];
  v += *(const f32x4*)&bias[tid * 4];
  const ushort4 p0 = *(const ushort4*)&parts[base];
  const ushort4 p1 = *(const ushort4*)&parts[(size_t)MM * DD + base];
  v[0] += b2f(p0.x) + b2f(p1.x);
  v[1] += b2f(p0.y) + b2f(p1.y);
  v[2] += b2f(p0.z) + b2f(p1.z);
  v[3] += b2f(p0.w) + b2f(p1.w);
  *(f32x4*)&hio[base] = v;
  float s = v[0] + v[1] + v[2] + v[3];
  float sq = v[0] * v[0] + v[1] * v[1] + v[2] * v[2] + v[3] * v[3];
#pragma unroll
  for (int off = 32; off; off >>= 1) {
    s += __shfl_xor(s, off);
    sq += __shfl_xor(sq, off);
  }
  __shared__ float ss[4], ssq[4];
  const int w = tid >> 6, lane = tid & 63;
  if (lane == 0) { ss[w] = s; ssq[w] = sq; }
  __syncthreads();
  s = ss[0] + ss[1] + ss[2] + ss[3];
  sq = ssq[0] + ssq[1] + ssq[2] + ssq[3];
  const float mean = s * (1.0f / DD);
  const float var = sq * (1.0f / DD) - mean * mean;
  const float rstd = rsqrtf(var + 1e-5f);
  const float4 gv = *(const float4*)&g[tid * 4];
  const float4 bv = *(const float4*)&be[tid * 4];
  ushort4 o;
  o.x = f2b((v[0] - mean) * rstd * gv.x + bv.x);
  o.y = f2b((v[1] - mean) * rstd * gv.y + bv.y);
  o.z = f2b((v[2] - mean) * rstd * gv.z + bv.z);
  o.w = f2b((v[3] - mean) * rstd * gv.w + bv.w);
  *(ushort4*)&out[(size_t)row * DD + tid * 4] = o;
}

// ------- 256x128 derived-waits GEMM, 3-slot ring, 64x64 wave tiles ---------
// (R14/R16 proven config). EPI: 0 = bf16 split-K partial @ out + ks*M*N;
// 1 = bf16+bias; 3 = bf16 GELU.
template <int EPI>
__global__ __launch_bounds__(512, 4) void gemm_dw3(const unsigned short* __restrict__ A,
                                                   const unsigned short* __restrict__ BT,
                                                   const float* __restrict__ bias,
                                                   void* __restrict__ outp,
                                                   int M, int N, int K,
                                                   int nbx, int nby, int ksplit,
                                                   int ksub) {
  __shared__ __align__(16) unsigned short lds[36864];  // 3 x 12288 shorts
  const int tid = threadIdx.x;
  const int lane = tid & 63;
  const int w = tid >> 6;
  // 2-D XCD region mapping (g_m=4, g_n=2), m-inner within region
  const int o = blockIdx.x;
  const int xcd = o & 7;
  const int j = o >> 3;
  const int m_per = (nby * ksplit) >> 2;  // nby_eff / g_m
  const int n_per = nbx >> 1;             // nbx / g_n
  const int m_loc = j % m_per, n_loc = j / m_per;
  const int m_idx = (xcd >> 1) * m_per + m_loc;
  const int n_idx = (xcd & 1) * n_per + n_loc;
  const int ks = m_idx / nby;
  const int mp = m_idx - ks * nby;
  const int n0 = n_idx * 128;
  const int m0 = mp * 256;
  const int kb = ks * ksub;
  const int wm = w >> 1, wn = w & 1;  // wave tile: 64 rows x 64 cols
  f32x4 acc[4][4] = {};

  const unsigned short* aSrc[2];
  const unsigned short* bSrc;
  int dstA[2], dstB;
#pragma unroll
  for (int i = 0; i < 2; i++) {
    const int s = tid + (i << 9);
    const int row = s >> 2, sc = s & 3;
    const int l = sc ^ ((row >> 1) & 3);
    aSrc[i] = &A[(size_t)(m0 + row) * K + kb + l * 8];
    dstA[i] = s * 8;
  }
  {
    const int row = tid >> 2, sc = tid & 3;
    const int l = sc ^ ((row >> 1) & 3);
    bSrc = &BT[(size_t)(n0 + row) * K + kb + l * 8];
    dstB = 8192 + tid * 8;
  }
  auto STAGE = [&](int u, int base) {
    const int kt = u << 5;
    gl_lds16(aSrc[0] + kt, &lds[base + dstA[0]]);
    gl_lds16(aSrc[1] + kt, &lds[base + dstA[1]]);
    gl_lds16(bSrc + kt, &lds[base + dstB]);
  };

  const int rA = lane & 15, cr = lane >> 4;
  const int rowA0 = wm * 64 + rA;
  const int rowB0 = wn * 64 + rA;
  const int aAddr0 = rowA0 * 32 + ((cr ^ ((rowA0 >> 1) & 3)) << 3);
  const int bAddr0 = 8192 + rowB0 * 32 + ((cr ^ ((rowB0 >> 1) & 3)) << 3);

  const int NS = ksub >> 5;  // slots (>= 16)
  int c0 = 0, c1 = 12288, c2 = 24576;
  STAGE(0, c0);
  STAGE(1, c1);

  for (int u = 0; u < NS; ++u) {
    if (u + 1 < NS) { WAITVM(3); } else { WAITVM(0); }
    __builtin_amdgcn_s_barrier();
    CFENCE;
    if (u + 2 < NS) STAGE(u + 2, c2);
    bf16x8 bfr[4], af[4];
#pragma unroll
    for (int n = 0; n < 4; n++) bfr[n] = ldsr(&lds[c0 + bAddr0 + n * 512]);
#pragma unroll
    for (int i = 0; i < 4; i++) af[i] = ldsr(&lds[c0 + aAddr0 + i * 512]);
    __builtin_amdgcn_s_setprio(1);
#pragma unroll
    for (int i = 0; i < 4; i++)
#pragma unroll
      for (int n = 0; n < 4; n++)
        acc[i][n] = __builtin_amdgcn_mfma_f32_16x16x32_bf16(af[i], bfr[n], acc[i][n], 0, 0, 0);
    __builtin_amdgcn_s_setprio(0);
    const int t = c0; c0 = c1; c1 = c2; c2 = t;  // rotate ring
  }

  const int r0 = (lane >> 4) * 4;
  const int cc = lane & 15;
#pragma unroll
  for (int m = 0; m < 4; m++)
#pragma unroll
    for (int n = 0; n < 4; n++)
#pragma unroll
      for (int r = 0; r < 4; r++) {
        const int row = m0 + wm * 64 + m * 16 + r0 + r;
        const int col = n0 + wn * 64 + n * 16 + cc;
        const size_t idx = (size_t)row * N + col;
        if (EPI == 0) {
          ((unsigned short*)outp)[(size_t)ks * M * N + idx] = f2b(acc[m][n][r]);
        } else {
          float val = acc[m][n][r] + bias[col];
          if (EPI == 3) {
            float u2 = val * (0.7978845608f + 0.0356774081f * val * val);
            u2 = fminf(u2, 10.0f);
            const float e = __expf(2.0f * u2);
            val = val * e / (e + 1.0f);
          }
          ((unsigned short*)outp)[idx] = f2b(val);
        }
      }
}

// ---------------- pipelined 128^2 bf16 MFMA GEMM (head only) ----------------
// writes bf16 split-K partials @ outp + ks*M*N
__global__ __launch_bounds__(512, 2) void gemm_p(const unsigned short* __restrict__ A,
                                                 const unsigned short* __restrict__ BT,
                                                 unsigned short* __restrict__ outp,
                                                 int M, int N, int K, int nbx, int nwg2,
                                                 int ksub) {
  constexpr int BM = 128;
  __shared__ __align__(16) unsigned short lds[4][BM * 64];
  const int tid = threadIdx.x;
  const int lane = tid & 63;
  const int w = tid >> 6;
  const int nwg = gridDim.x;
  const int orig = blockIdx.x;
  const int wg = (orig & 7) * (nwg >> 3) + (orig >> 3);
  const int ks = wg / nwg2;
  const int rem = wg - ks * nwg2;
  const int n0 = (rem % nbx) * BM;
  const int m0 = (rem / nbx) * BM;
  const int kb = ks * ksub;
  const int wm = w >> 2, wn = w & 3;
  f32x4 acc[4][2] = {};

  auto STAGE = [&](int t) {
    const int b = t & 3;
    const int kt = kb + (t << 5);
    const int s = tid;
    const int row = s >> 2, sc = s & 3;
    const int c = sc ^ ((row >> 1) & 3);
    gl_lds16(&A[(size_t)(m0 + row) * K + kt + c * 8], &lds[b][s * 8]);
    gl_lds16(&BT[(size_t)(n0 + row) * K + kt + c * 8], &lds[b][BM * 32 + s * 8]);
  };

  const int NT = ksub >> 5;
  STAGE(0); STAGE(1); STAGE(2);

  for (int t = 0; t < NT; ++t) {
    const int ahead = NT - 1 - t;
    if (ahead >= 2) WAITVM(4); else if (ahead == 1) WAITVM(2); else WAITVM(0);
    __builtin_amdgcn_s_barrier();
    CFENCE;
    if (t + 3 < NT) STAGE(t + 3);
    const int b = t & 3;
    const int rA = lane & 15, cr = lane >> 4;
    bf16x8 af[4], bfr[2];
#pragma unroll
    for (int m = 0; m < 4; m++) {
      const int row = wm * 64 + m * 16 + rA;
      af[m] = ldsr(&lds[b][row * 32 + ((cr ^ ((row >> 1) & 3)) << 3)]);
    }
#pragma unroll
    for (int n = 0; n < 2; n++) {
      const int row = wn * 32 + n * 16 + rA;
      bfr[n] = ldsr(&lds[b][BM * 32 + row * 32 + ((cr ^ ((row >> 1) & 3)) << 3)]);
    }
    __builtin_amdgcn_s_setprio(1);
#pragma unroll
    for (int m = 0; m < 4; m++)
#pragma unroll
      for (int n = 0; n < 2; n++)
        acc[m][n] = __builtin_amdgcn_mfma_f32_16x16x32_bf16(af[m], bfr[n], acc[m][n], 0, 0, 0);
    __builtin_amdgcn_s_setprio(0);
  }

  const int r0 = (lane >> 4) * 4;
  const int cc = lane & 15;
  unsigned short* pout = outp + (size_t)ks * M * N;
#pragma unroll
  for (int m = 0; m < 4; m++)
#pragma unroll
    for (int n = 0; n < 2; n++)
#pragma unroll
      for (int r = 0; r < 4; r++) {
        const int row = m0 + wm * 64 + m * 16 + r0 + r;
        const int col = n0 + wn * 32 + n * 16 + cc;
        pout[(size_t)row * N + col] = f2b(acc[m][n][r]);
      }
}

// ---------------- reduce: dst(f32) = sum(bf16 parts) ----------------
template <int NP>
__global__ __launch_bounds__(256) void reduce_k(float* __restrict__ dst,
                                                const unsigned short* __restrict__ parts,
                                                size_t total) {
  const size_t i = ((size_t)blockIdx.x * 256 + threadIdx.x) * 4;
  if (i >= total) return;
  f32x4 acc = {};
#pragma unroll
  for (int p = 0; p < NP; p++) {
    const ushort4 pv = *(const ushort4*)&parts[(size_t)p * total + i];
    acc[0] += b2f(pv.x);
    acc[1] += b2f(pv.y);
    acc[2] += b2f(pv.z);
    acc[3] += b2f(pv.w);
  }
  *(f32x4*)&dst[i] = acc;
}

// ---------------- MFMA sparse attention (fused-QKV input, stride QS) ----------------
#define QT 16
#define KT 32
#define NTMAX 6
#define KP 72   // padded K/V tile row (shorts)
#define PP 40   // padded P row (shorts)

__global__ __launch_bounds__(256) void attn_mfma(const unsigned short* __restrict__ qkv,
                                                 unsigned short* __restrict__ outg) {
  __shared__ __align__(16) unsigned short kvs[4][KT * KP];
  __shared__ __align__(16) unsigned short pls[4][QT * PP];
  const int tid = threadIdx.x;
  const int wid = tid >> 6, lane = tid & 63;
  const int qgrp = blockIdx.x & 31;
  const int bh = blockIdx.x >> 5;
  const int h = bh & (HH - 1), b = bh >> 4;
  const size_t baseq = (size_t)b * TT * QS + (size_t)h * HD;
  const size_t baseo = (size_t)b * TT * DD + (size_t)h * HD;
  const int i0 = qgrp * 64 + wid * 16;
  const int g = lane >> 4;
  const int c = lane & 15;

  const int i0b = qgrp * 64 + 48;
  const int ka0b = (i0b > 128) ? ((i0b - 128) & ~31) : 0;
  const int nlb = ((i0b + 16 - ka0b) + 31) >> 5;
  const int neb = (ka0b + 255) >> 8;
  const int ka0 = (i0 > 128) ? ((i0 - 128) & ~31) : 0;
  const int ne = (ka0 + 255) >> 8;

  const s16x8 qf0 = *(const s16x8*)&qkv[baseq + (size_t)(i0 + c) * QS + g * 8];
  const s16x8 qf1 = *(const s16x8*)&qkv[baseq + (size_t)(i0 + c) * QS + 32 + g * 8];

  f32x4 sc[NTMAX][2];
  float smax[4] = {-1e30f, -1e30f, -1e30f, -1e30f};

#pragma unroll
  for (int t = 0; t < NTMAX; t++) {
    if (t > nlb) continue;
    const bool isg = (t == 0);
    if (isg && neb == 0) continue;
    const int kt0 = ka0 + (t - 1) * 32;
#pragma unroll
    for (int it = 0; it < 4; it++) {
      const int row = it * 8 + (lane >> 3);
      const int ch = lane & 7;
      const int j = isg ? ((row < ne) ? row * STRIDE_G : 0) : (kt0 + row);
      *(s16x8*)&kvs[wid][row * KP + ch * 8] =
          *(const s16x8*)&qkv[baseq + DD + (size_t)j * QS + ch * 8];
    }
    __syncthreads();
#pragma unroll
    for (int half = 0; half < 2; half++) {
      const int key = half * 16 + c;
      const bf16x8 kb0 = __builtin_bit_cast(bf16x8, *(const s16x8*)&kvs[wid][key * KP + g * 8]);
      const bf16x8 kb1 = __builtin_bit_cast(bf16x8, *(const s16x8*)&kvs[wid][key * KP + 32 + g * 8]);
      f32x4 a = {};
      a = __builtin_amdgcn_mfma_f32_16x16x32_bf16(__builtin_bit_cast(bf16x8, qf0), kb0, a, 0, 0, 0);
      a = __builtin_amdgcn_mfma_f32_16x16x32_bf16(__builtin_bit_cast(bf16x8, qf1), kb1, a, 0, 0, 0);
#pragma unroll
      for (int r = 0; r < 4; r++) {
        const int i = i0 + g * 4 + r;
        bool ok;
        if (isg) {
          ok = (key < ne);
        } else {
          const int j = kt0 + key;
          ok = (j <= i) && (((i - j) <= LOCAL_W) || ((j & (STRIDE_G - 1)) == 0));
        }
        const float s = ok ? a[r] * 0.125f : -1e30f;
        sc[t][half][r] = s;
        smax[r] = fmaxf(smax[r], s);
      }
    }
    __syncthreads();
  }
#pragma unroll
  for (int r = 0; r < 4; r++)
#pragma unroll
    for (int off = 8; off; off >>= 1)
      smax[r] = fmaxf(smax[r], __shfl_xor(smax[r], off));

  f32x4 o[4] = {};
  float lsum[4] = {0.f, 0.f, 0.f, 0.f};
#pragma unroll
  for (int t = 0; t < NTMAX; t++) {
    if (t > nlb) continue;
    const bool isg = (t == 0);
    if (isg && neb == 0) continue;
    const int kt0 = ka0 + (t - 1) * 32;
#pragma unroll
    for (int it = 0; it < 4; it++) {
      const int row = it * 8 + (lane >> 3);
      const int ch = lane & 7;
      const int j = isg ? ((row < ne) ? row * STRIDE_G : 0) : (kt0 + row);
      *(s16x8*)&kvs[wid][row * KP + ch * 8] =
          *(const s16x8*)&qkv[baseq + 2 * DD + (size_t)j * QS + ch * 8];
    }
#pragma unroll
    for (int half = 0; half < 2; half++)
#pragma unroll
      for (int r = 0; r < 4; r++) {
        const float p = __expf(sc[t][half][r] - smax[r]);
        lsum[r] += p;
        pls[wid][(g * 4 + r) * PP + half * 16 + c] = f2b(p);
      }
    __syncthreads();
    const bf16x8 pa = __builtin_bit_cast(bf16x8, *(const s16x8*)&pls[wid][c * PP + g * 8]);
#pragma unroll
    for (int d0 = 0; d0 < 4; d0++) {
      s16x8 bv;
#pragma unroll
      for (int e = 0; e < 8; e++)
        bv[e] = (short)kvs[wid][(g * 8 + e) * KP + d0 * 16 + c];
      o[d0] = __builtin_amdgcn_mfma_f32_16x16x32_bf16(pa, __builtin_bit_cast(bf16x8, bv), o[d0], 0, 0, 0);
    }
    __syncthreads();
  }
#pragma unroll
  for (int r = 0; r < 4; r++)
#pragma unroll
    for (int off = 8; off; off >>= 1)
      lsum[r] += __shfl_xor(lsum[r], off);
#pragma unroll
  for (int d0 = 0; d0 < 4; d0++)
#pragma unroll
    for (int r = 0; r < 4; r++)
      outg[baseo + (size_t)(i0 + g * 4 + r) * DD + d0 * 16 + c] = f2b(o[d0][r] / lsum[r]);
}

// ---------------- host ----------------
extern "C" void kernel_launch(void* const* d_in, const int* in_sizes, int n_in,
                              void* d_out, int out_size, void* d_ws, size_t ws_size,
                              hipStream_t stream) {
  const int* x = (const int*)d_in[0];
  const float* embed = (const float*)d_in[1];
  const float* pos = (const float*)d_in[2];
  const float* Wq = (const float*)d_in[3];
  const float* bq = (const float*)d_in[4];
  const float* Wk = (const float*)d_in[5];
  const float* bk = (const float*)d_in[6];
  const float* Wv = (const float*)d_in[7];
  const float* bv = (const float*)d_in[8];
  const float* Wo = (const float*)d_in[9];
  const float* bo = (const float*)d_in[10];
  const float* g1 = (const float*)d_in[11];
  const float* be1 = (const float*)d_in[12];
  const float* W1 = (const float*)d_in[13];
  const float* bf1 = (const float*)d_in[14];
  const float* W2 = (const float*)d_in[15];
  const float* bf2 = (const float*)d_in[16];
  const float* g2 = (const float*)d_in[17];
  const float* be2 = (const float*)d_in[18];
  const float* gf = (const float*)d_in[19];
  const float* bef = (const float*)d_in[20];
  const float* Whead = (const float*)d_in[21];

  char* ws = (char*)d_ws;
  size_t off = 0;
  auto alloc = [&](size_t bytes) -> void* {
    void* p = ws + off;
    off += (bytes + 255) & ~(size_t)255;
    return p;
  };
  unsigned short* WqkvT = (unsigned short*)alloc((size_t)2 * QS * DD * 2);
  unsigned short* WoT = (unsigned short*)alloc((size_t)2 * DD * DD * 2);
  unsigned short* W1T = (unsigned short*)alloc((size_t)2 * DD * FF * 2);
  unsigned short* W2T = (unsigned short*)alloc((size_t)2 * DD * FF * 2);
  unsigned short* WheadT = (unsigned short*)alloc((size_t)DD * VV * 2);
  float* bcat = (float*)alloc((size_t)2 * QS * 4);
  float* h = (float*)alloc((size_t)MM * DD * 4);
  unsigned short* hn = (unsigned short*)alloc((size_t)MM * DD * 2);
  unsigned short* qkvb = (unsigned short*)alloc((size_t)MM * QS * 2);   // 24 MB
  unsigned short* attnb = (unsigned short*)alloc((size_t)MM * DD * 2);  // 8 MB
  unsigned short* mid = (unsigned short*)alloc((size_t)MM * FF * 2);    // 32 MB
  unsigned short* ffn2p = qkvb;   // 2 x [MM x DD] bf16 = 16 MB overlay (qkvb dead)
  unsigned short* oprojp = mid;   // 2 x [MM x DD] bf16 = 16 MB overlay (mid dead)
  unsigned short* headp = mid;    // 4 x [MM x VV] bf16 = 8 MB <= mid
  (void)ws_size;

  const dim3 tb(32, 8);
  qkv_t<<<dim3(DD / 32, DD / 32, 6), tb, 0, stream>>>(Wq, Wk, Wv, WqkvT);
  transpose_k<<<dim3(DD / 32, DD / 32, 2), tb, 0, stream>>>(Wo, WoT, DD, DD,
                                                            (size_t)DD * DD, (size_t)DD * DD);
  transpose_k<<<dim3(FF / 32, DD / 32, 2), tb, 0, stream>>>(W1, W1T, DD, FF,
                                                            (size_t)DD * FF, (size_t)DD * FF);
  transpose_k<<<dim3(DD / 32, FF / 32, 2), tb, 0, stream>>>(W2, W2T, FF, DD,
                                                            (size_t)DD * FF, (size_t)DD * FF);
  transpose_k<<<dim3(VV / 32, DD / 32, 1), tb, 0, stream>>>(Whead, WheadT, DD, VV, 0, 0);
  concat_bias<<<24, 256, 0, stream>>>(bq, bk, bv, bcat);

  embed_ln<<<MM, 256, 0, stream>>>(x, embed, pos, g1, be1, h, hn);

  for (int l = 0; l < 2; l++) {
    const size_t wo = (size_t)l * DD * DD;
    const size_t wf = (size_t)l * DD * FF;
    // fused QKV: grid 384 = 8 * (16/4) * (24/2)
    gemm_dw3<1><<<(QS / 128) * (MM / 256), 512, 0, stream>>>(
        hn, WqkvT + (size_t)l * QS * DD, bcat + l * QS, qkvb,
        MM, QS, DD, QS / 128, MM / 256, 1, DD);
    attn_mfma<<<BB * HH * (TT / 64), 256, 0, stream>>>(qkvb, attnb);
    // O-proj: split-K=2, grid 256 = 8 * (32/4) * (8/2) -> bf16 partials in mid
    gemm_dw3<0><<<2 * (DD / 128) * (MM / 256), 512, 0, stream>>>(
        attnb, WoT + wo, nullptr, oprojp,
        MM, DD, DD, DD / 128, MM / 256, 2, DD / 2);
    ln_red<<<MM, 256, 0, stream>>>(h, oprojp, bo + l * DD, g2 + l * DD, be2 + l * DD, hn);
    // FFN1: GELU, grid 512 = 8 * (16/4) * (32/2)
    gemm_dw3<3><<<(FF / 128) * (MM / 256), 512, 0, stream>>>(
        hn, W1T + wf, bf1 + l * FF, mid,
        MM, FF, DD, FF / 128, MM / 256, 1, DD);
    // FFN2: split-K=2, grid 256 -> bf16 partials
    gemm_dw3<0><<<2 * (DD / 128) * (MM / 256), 512, 0, stream>>>(
        mid, W2T + wf, nullptr, ffn2p,
        MM, DD, FF, DD / 128, MM / 256, 2, FF / 2);
    if (l == 0)
      ln_red<<<MM, 256, 0, stream>>>(h, ffn2p, bf2, g1 + DD, be1 + DD, hn);
    else
      ln_red<<<MM, 256, 0, stream>>>(h, ffn2p, bf2 + DD, gf, bef, hn);
  }
  // head split-K=4 -> bf16 partials -> d_out (f32)
  gemm_p<<<4 * (VV / 128) * (MM / 128), 512, 0, stream>>>(
      hn, WheadT, headp, MM, VV, DD, VV / 128, (VV / 128) * (MM / 128), DD / 4);
  reduce_k<4><<<(MM * VV) / 1024, 256, 0, stream>>>(
      (float*)d_out, headp, (size_t)MM * VV);
}

// Round 18
// 403.671 us; speedup vs baseline: 1.1174x; 1.0336x over previous
//
#include <hip/hip_runtime.h>
#include <hip/hip_bf16.h>

// ---------------- problem constants ----------------
#define BB 2
#define TT 2048
#define DD 1024
#define FF 4096
#define VV 256
#define HH 16
#define HD 64
#define MM (BB * TT)      // 4096 rows
#define LOCAL_W 128
#define STRIDE_G 256
#define QS 3072           // fused QKV row stride

typedef short s16x8 __attribute__((ext_vector_type(8)));
typedef __bf16 bf16x8 __attribute__((ext_vector_type(8)));
typedef float f32x4 __attribute__((ext_vector_type(4)));

#define WAITVM(N) asm volatile("s_waitcnt vmcnt(" #N ")" ::: "memory")
#define CFENCE asm volatile("" ::: "memory")

__device__ __forceinline__ float b2f(unsigned short u) {
  return __builtin_bit_cast(float, (unsigned int)u << 16);
}
__device__ __forceinline__ unsigned short f2b(float f) {
  __hip_bfloat16 h = __float2bfloat16(f);  // RNE
  return __builtin_bit_cast(unsigned short, h);
}
// async global->LDS, 16B per lane; LDS dest = wave-uniform base + lane*16
__device__ __forceinline__ void gl_lds16(const unsigned short* g, unsigned short* l) {
  __builtin_amdgcn_global_load_lds(
      (const __attribute__((address_space(1))) void*)g,
      (__attribute__((address_space(3))) void*)l, 16, 0, 0);
}
__device__ __forceinline__ bf16x8 ldsr(const unsigned short* p) {
  return __builtin_bit_cast(bf16x8, *(const s16x8*)p);
}

// ------- batched weight transpose f32[K][N] -> bf16[N][K], z = batch -------
__global__ __launch_bounds__(256) void transpose_k(const float* __restrict__ W,
                                                   unsigned short* __restrict__ WT,
                                                   int K, int N,
                                                   size_t sstride, size_t dstride) {
  __shared__ float t[32][33];
  const int z = blockIdx.z;
  W += (size_t)z * sstride;
  WT += (size_t)z * dstride;
  const int n0 = blockIdx.x * 32, k0 = blockIdx.y * 32;
  const int tx = threadIdx.x, ty = threadIdx.y;  // (32, 8)
  for (int r = ty; r < 32; r += 8) t[r][tx] = W[(size_t)(k0 + r) * N + n0 + tx];
  __syncthreads();
  for (int r = ty; r < 32; r += 8)
    WT[(size_t)(n0 + r) * K + k0 + tx] = f2b(t[tx][r]);
}

// ------- QKV transpose: z in 0..5 = (layer, which) -> WqkvT[l][3DD][DD] ----
__global__ __launch_bounds__(256) void qkv_t(const float* __restrict__ Wq,
                                             const float* __restrict__ Wk,
                                             const float* __restrict__ Wv,
                                             unsigned short* __restrict__ WT) {
  __shared__ float t[32][33];
  const int z = blockIdx.z;
  const int l = z / 3, which = z % 3;
  const float* W = (which == 0 ? Wq : which == 1 ? Wk : Wv) + (size_t)l * DD * DD;
  unsigned short* D = WT + ((size_t)l * QS + which * DD) * DD;
  const int n0 = blockIdx.x * 32, k0 = blockIdx.y * 32;
  const int tx = threadIdx.x, ty = threadIdx.y;
  for (int r = ty; r < 32; r += 8) t[r][tx] = W[(size_t)(k0 + r) * DD + n0 + tx];
  __syncthreads();
  for (int r = ty; r < 32; r += 8)
    D[(size_t)(n0 + r) * DD + k0 + tx] = f2b(t[tx][r]);
}

// ---------------- concat QKV bias: bcat[l][3072] ----------------
__global__ __launch_bounds__(256) void concat_bias(const float* __restrict__ bq,
                                                   const float* __restrict__ bk,
                                                   const float* __restrict__ bv,
                                                   float* __restrict__ bcat) {
  const int i = blockIdx.x * 256 + threadIdx.x;  // 6144 total
  const int l = i / QS, j = i - l * QS;
  float v;
  if (j < DD) v = bq[l * DD + j];
  else if (j < 2 * DD) v = bk[l * DD + j - DD];
  else v = bv[l * DD + j - 2 * DD];
  bcat[i] = v;
}

// ------- fused embedding + positional + layer-0 LN1 (bf16 h + hn out) ------
__global__ __launch_bounds__(256) void embed_ln(const int* __restrict__ x,
                                                const float* __restrict__ emb,
                                                const float* __restrict__ pos,
                                                const float* __restrict__ g,
                                                const float* __restrict__ be,
                                                unsigned short* __restrict__ hb,
                                                unsigned short* __restrict__ out) {
  const int row = blockIdx.x;
  const int tid = threadIdx.x;
  const int tok = x[row];
  const int t = row & (TT - 1);
  f32x4 v = *(const f32x4*)&emb[(size_t)tok * DD + tid * 4];
  v += *(const f32x4*)&pos[(size_t)t * DD + tid * 4];
  ushort4 hv;
  hv.x = f2b(v[0]); hv.y = f2b(v[1]); hv.z = f2b(v[2]); hv.w = f2b(v[3]);
  *(ushort4*)&hb[(size_t)row * DD + tid * 4] = hv;
  float s = v[0] + v[1] + v[2] + v[3];
  float sq = v[0] * v[0] + v[1] * v[1] + v[2] * v[2] + v[3] * v[3];
#pragma unroll
  for (int off = 32; off; off >>= 1) {
    s += __shfl_xor(s, off);
    sq += __shfl_xor(sq, off);
  }
  __shared__ float ss[4], ssq[4];
  const int w = tid >> 6, lane = tid & 63;
  if (lane == 0) { ss[w] = s; ssq[w] = sq; }
  __syncthreads();
  s = ss[0] + ss[1] + ss[2] + ss[3];
  sq = ssq[0] + ssq[1] + ssq[2] + ssq[3];
  const float mean = s * (1.0f / DD);
  const float var = sq * (1.0f / DD) - mean * mean;
  const float rstd = rsqrtf(var + 1e-5f);
  const float4 gv = *(const float4*)&g[tid * 4];
  const float4 bv = *(const float4*)&be[tid * 4];
  ushort4 o;
  o.x = f2b((v[0] - mean) * rstd * gv.x + bv.x);
  o.y = f2b((v[1] - mean) * rstd * gv.y + bv.y);
  o.z = f2b((v[2] - mean) * rstd * gv.z + bv.z);
  o.w = f2b((v[3] - mean) * rstd * gv.w + bv.w);
  *(ushort4*)&out[(size_t)row * DD + tid * 4] = o;
}

// ---- fused split-K reduce (bf16 partials) + bf16 residual + LayerNorm ----
__global__ __launch_bounds__(256) void ln_red(unsigned short* __restrict__ hio,
                                              const unsigned short* __restrict__ parts,
                                              const float* __restrict__ bias,
                                              const float* __restrict__ g,
                                              const float* __restrict__ be,
                                              unsigned short* __restrict__ out) {
  const int row = blockIdx.x;
  const int tid = threadIdx.x;
  const size_t base = (size_t)row * DD + tid * 4;
  const ushort4 hv = *(const ushort4*)&hio[base];
  f32x4 v;
  v[0] = b2f(hv.x); v[1] = b2f(hv.y); v[2] = b2f(hv.z); v[3] = b2f(hv.w);
  v += *(const f32x4*)&bias[tid * 4];
  const ushort4 p0 = *(const ushort4*)&parts[base];
  const ushort4 p1 = *(const ushort4*)&parts[(size_t)MM * DD + base];
  v[0] += b2f(p0.x) + b2f(p1.x);
  v[1] += b2f(p0.y) + b2f(p1.y);
  v[2] += b2f(p0.z) + b2f(p1.z);
  v[3] += b2f(p0.w) + b2f(p1.w);
  ushort4 hw;
  hw.x = f2b(v[0]); hw.y = f2b(v[1]); hw.z = f2b(v[2]); hw.w = f2b(v[3]);
  *(ushort4*)&hio[base] = hw;
  float s = v[0] + v[1] + v[2] + v[3];
  float sq = v[0] * v[0] + v[1] * v[1] + v[2] * v[2] + v[3] * v[3];
#pragma unroll
  for (int off = 32; off; off >>= 1) {
    s += __shfl_xor(s, off);
    sq += __shfl_xor(sq, off);
  }
  __shared__ float ss[4], ssq[4];
  const int w = tid >> 6, lane = tid & 63;
  if (lane == 0) { ss[w] = s; ssq[w] = sq; }
  __syncthreads();
  s = ss[0] + ss[1] + ss[2] + ss[3];
  sq = ssq[0] + ssq[1] + ssq[2] + ssq[3];
  const float mean = s * (1.0f / DD);
  const float var = sq * (1.0f / DD) - mean * mean;
  const float rstd = rsqrtf(var + 1e-5f);
  const float4 gv = *(const float4*)&g[tid * 4];
  const float4 bv = *(const float4*)&be[tid * 4];
  ushort4 o;
  o.x = f2b((v[0] - mean) * rstd * gv.x + bv.x);
  o.y = f2b((v[1] - mean) * rstd * gv.y + bv.y);
  o.z = f2b((v[2] - mean) * rstd * gv.z + bv.z);
  o.w = f2b((v[3] - mean) * rstd * gv.w + bv.w);
  *(ushort4*)&out[(size_t)row * DD + tid * 4] = o;
}

// ------- 256x128 derived-waits GEMM, 3-slot ring, 64x64 wave tiles ---------
// (R14/R16 proven config). EPI: 0 = bf16 split-K partial @ out + ks*M*N;
// 1 = bf16+bias; 3 = bf16 GELU.
template <int EPI>
__global__ __launch_bounds__(512, 4) void gemm_dw3(const unsigned short* __restrict__ A,
                                                   const unsigned short* __restrict__ BT,
                                                   const float* __restrict__ bias,
                                                   void* __restrict__ outp,
                                                   int M, int N, int K,
                                                   int nbx, int nby, int ksplit,
                                                   int ksub) {
  __shared__ __align__(16) unsigned short lds[36864];  // 3 x 12288 shorts
  const int tid = threadIdx.x;
  const int lane = tid & 63;
  const int w = tid >> 6;
  // 2-D XCD region mapping (g_m=4, g_n=2), m-inner within region
  const int o = blockIdx.x;
  const int xcd = o & 7;
  const int j = o >> 3;
  const int m_per = (nby * ksplit) >> 2;  // nby_eff / g_m
  const int n_per = nbx >> 1;             // nbx / g_n
  const int m_loc = j % m_per, n_loc = j / m_per;
  const int m_idx = (xcd >> 1) * m_per + m_loc;
  const int n_idx = (xcd & 1) * n_per + n_loc;
  const int ks = m_idx / nby;
  const int mp = m_idx - ks * nby;
  const int n0 = n_idx * 128;
  const int m0 = mp * 256;
  const int kb = ks * ksub;
  const int wm = w >> 1, wn = w & 1;  // wave tile: 64 rows x 64 cols
  f32x4 acc[4][4] = {};

  const unsigned short* aSrc[2];
  const unsigned short* bSrc;
  int dstA[2], dstB;
#pragma unroll
  for (int i = 0; i < 2; i++) {
    const int s = tid + (i << 9);
    const int row = s >> 2, sc = s & 3;
    const int l = sc ^ ((row >> 1) & 3);
    aSrc[i] = &A[(size_t)(m0 + row) * K + kb + l * 8];
    dstA[i] = s * 8;
  }
  {
    const int row = tid >> 2, sc = tid & 3;
    const int l = sc ^ ((row >> 1) & 3);
    bSrc = &BT[(size_t)(n0 + row) * K + kb + l * 8];
    dstB = 8192 + tid * 8;
  }
  auto STAGE = [&](int u, int base) {
    const int kt = u << 5;
    gl_lds16(aSrc[0] + kt, &lds[base + dstA[0]]);
    gl_lds16(aSrc[1] + kt, &lds[base + dstA[1]]);
    gl_lds16(bSrc + kt, &lds[base + dstB]);
  };

  const int rA = lane & 15, cr = lane >> 4;
  const int rowA0 = wm * 64 + rA;
  const int rowB0 = wn * 64 + rA;
  const int aAddr0 = rowA0 * 32 + ((cr ^ ((rowA0 >> 1) & 3)) << 3);
  const int bAddr0 = 8192 + rowB0 * 32 + ((cr ^ ((rowB0 >> 1) & 3)) << 3);

  const int NS = ksub >> 5;  // slots (>= 16)
  int c0 = 0, c1 = 12288, c2 = 24576;
  STAGE(0, c0);
  STAGE(1, c1);

  for (int u = 0; u < NS; ++u) {
    if (u + 1 < NS) { WAITVM(3); } else { WAITVM(0); }
    __builtin_amdgcn_s_barrier();
    CFENCE;
    if (u + 2 < NS) STAGE(u + 2, c2);
    bf16x8 bfr[4], af[4];
#pragma unroll
    for (int n = 0; n < 4; n++) bfr[n] = ldsr(&lds[c0 + bAddr0 + n * 512]);
#pragma unroll
    for (int i = 0; i < 4; i++) af[i] = ldsr(&lds[c0 + aAddr0 + i * 512]);
    __builtin_amdgcn_s_setprio(1);
#pragma unroll
    for (int i = 0; i < 4; i++)
#pragma unroll
      for (int n = 0; n < 4; n++)
        acc[i][n] = __builtin_amdgcn_mfma_f32_16x16x32_bf16(af[i], bfr[n], acc[i][n], 0, 0, 0);
    __builtin_amdgcn_s_setprio(0);
    const int t = c0; c0 = c1; c1 = c2; c2 = t;  // rotate ring
  }

  const int r0 = (lane >> 4) * 4;
  const int cc = lane & 15;
#pragma unroll
  for (int m = 0; m < 4; m++)
#pragma unroll
    for (int n = 0; n < 4; n++)
#pragma unroll
      for (int r = 0; r < 4; r++) {
        const int row = m0 + wm * 64 + m * 16 + r0 + r;
        const int col = n0 + wn * 64 + n * 16 + cc;
        const size_t idx = (size_t)row * N + col;
        if (EPI == 0) {
          ((unsigned short*)outp)[(size_t)ks * M * N + idx] = f2b(acc[m][n][r]);
        } else {
          float val = acc[m][n][r] + bias[col];
          if (EPI == 3) {
            float u2 = val * (0.7978845608f + 0.0356774081f * val * val);
            u2 = fminf(u2, 10.0f);
            const float e = __expf(2.0f * u2);
            val = val * e / (e + 1.0f);
          }
          ((unsigned short*)outp)[idx] = f2b(val);
        }
      }
}

// ---------------- pipelined 128^2 bf16 MFMA GEMM (head only) ----------------
// writes bf16 split-K partials @ outp + ks*M*N
__global__ __launch_bounds__(512, 2) void gemm_p(const unsigned short* __restrict__ A,
                                                 const unsigned short* __restrict__ BT,
                                                 unsigned short* __restrict__ outp,
                                                 int M, int N, int K, int nbx, int nwg2,
                                                 int ksub) {
  constexpr int BM = 128;
  __shared__ __align__(16) unsigned short lds[4][BM * 64];
  const int tid = threadIdx.x;
  const int lane = tid & 63;
  const int w = tid >> 6;
  const int nwg = gridDim.x;
  const int orig = blockIdx.x;
  const int wg = (orig & 7) * (nwg >> 3) + (orig >> 3);
  const int ks = wg / nwg2;
  const int rem = wg - ks * nwg2;
  const int n0 = (rem % nbx) * BM;
  const int m0 = (rem / nbx) * BM;
  const int kb = ks * ksub;
  const int wm = w >> 2, wn = w & 3;
  f32x4 acc[4][2] = {};

  auto STAGE = [&](int t) {
    const int b = t & 3;
    const int kt = kb + (t << 5);
    const int s = tid;
    const int row = s >> 2, sc = s & 3;
    const int c = sc ^ ((row >> 1) & 3);
    gl_lds16(&A[(size_t)(m0 + row) * K + kt + c * 8], &lds[b][s * 8]);
    gl_lds16(&BT[(size_t)(n0 + row) * K + kt + c * 8], &lds[b][BM * 32 + s * 8]);
  };

  const int NT = ksub >> 5;
  STAGE(0); STAGE(1); STAGE(2);

  for (int t = 0; t < NT; ++t) {
    const int ahead = NT - 1 - t;
    if (ahead >= 2) WAITVM(4); else if (ahead == 1) WAITVM(2); else WAITVM(0);
    __builtin_amdgcn_s_barrier();
    CFENCE;
    if (t + 3 < NT) STAGE(t + 3);
    const int b = t & 3;
    const int rA = lane & 15, cr = lane >> 4;
    bf16x8 af[4], bfr[2];
#pragma unroll
    for (int m = 0; m < 4; m++) {
      const int row = wm * 64 + m * 16 + rA;
      af[m] = ldsr(&lds[b][row * 32 + ((cr ^ ((row >> 1) & 3)) << 3)]);
    }
#pragma unroll
    for (int n = 0; n < 2; n++) {
      const int row = wn * 32 + n * 16 + rA;
      bfr[n] = ldsr(&lds[b][BM * 32 + row * 32 + ((cr ^ ((row >> 1) & 3)) << 3)]);
    }
    __builtin_amdgcn_s_setprio(1);
#pragma unroll
    for (int m = 0; m < 4; m++)
#pragma unroll
      for (int n = 0; n < 2; n++)
        acc[m][n] = __builtin_amdgcn_mfma_f32_16x16x32_bf16(af[m], bfr[n], acc[m][n], 0, 0, 0);
    __builtin_amdgcn_s_setprio(0);
  }

  const int r0 = (lane >> 4) * 4;
  const int cc = lane & 15;
  unsigned short* pout = outp + (size_t)ks * M * N;
#pragma unroll
  for (int m = 0; m < 4; m++)
#pragma unroll
    for (int n = 0; n < 2; n++)
#pragma unroll
      for (int r = 0; r < 4; r++) {
        const int row = m0 + wm * 64 + m * 16 + r0 + r;
        const int col = n0 + wn * 32 + n * 16 + cc;
        pout[(size_t)row * N + col] = f2b(acc[m][n][r]);
      }
}

// ---------------- reduce: dst(f32) = sum(bf16 parts) ----------------
template <int NP>
__global__ __launch_bounds__(256) void reduce_k(float* __restrict__ dst,
                                                const unsigned short* __restrict__ parts,
                                                size_t total) {
  const size_t i = ((size_t)blockIdx.x * 256 + threadIdx.x) * 4;
  if (i >= total) return;
  f32x4 acc = {};
#pragma unroll
  for (int p = 0; p < NP; p++) {
    const ushort4 pv = *(const ushort4*)&parts[(size_t)p * total + i];
    acc[0] += b2f(pv.x);
    acc[1] += b2f(pv.y);
    acc[2] += b2f(pv.z);
    acc[3] += b2f(pv.w);
  }
  *(f32x4*)&dst[i] = acc;
}

// ---------------- MFMA sparse attention (fused-QKV input, stride QS) ----------------
#define QT 16
#define KT 32
#define NTMAX 6
#define KP 72   // padded K/V tile row (shorts)
#define PP 40   // padded P row (shorts)

__global__ __launch_bounds__(256) void attn_mfma(const unsigned short* __restrict__ qkv,
                                                 unsigned short* __restrict__ outg) {
  __shared__ __align__(16) unsigned short kvs[4][KT * KP];
  __shared__ __align__(16) unsigned short pls[4][QT * PP];
  const int tid = threadIdx.x;
  const int wid = tid >> 6, lane = tid & 63;
  const int qgrp = blockIdx.x & 31;
  const int bh = blockIdx.x >> 5;
  const int h = bh & (HH - 1), b = bh >> 4;
  const size_t baseq = (size_t)b * TT * QS + (size_t)h * HD;
  const size_t baseo = (size_t)b * TT * DD + (size_t)h * HD;
  const int i0 = qgrp * 64 + wid * 16;
  const int g = lane >> 4;
  const int c = lane & 15;

  const int i0b = qgrp * 64 + 48;
  const int ka0b = (i0b > 128) ? ((i0b - 128) & ~31) : 0;
  const int nlb = ((i0b + 16 - ka0b) + 31) >> 5;
  const int neb = (ka0b + 255) >> 8;
  const int ka0 = (i0 > 128) ? ((i0 - 128) & ~31) : 0;
  const int ne = (ka0 + 255) >> 8;

  const s16x8 qf0 = *(const s16x8*)&qkv[baseq + (size_t)(i0 + c) * QS + g * 8];
  const s16x8 qf1 = *(const s16x8*)&qkv[baseq + (size_t)(i0 + c) * QS + 32 + g * 8];

  f32x4 sc[NTMAX][2];
  float smax[4] = {-1e30f, -1e30f, -1e30f, -1e30f};

#pragma unroll
  for (int t = 0; t < NTMAX; t++) {
    if (t > nlb) continue;
    const bool isg = (t == 0);
    if (isg && neb == 0) continue;
    const int kt0 = ka0 + (t - 1) * 32;
#pragma unroll
    for (int it = 0; it < 4; it++) {
      const int row = it * 8 + (lane >> 3);
      const int ch = lane & 7;
      const int j = isg ? ((row < ne) ? row * STRIDE_G : 0) : (kt0 + row);
      *(s16x8*)&kvs[wid][row * KP + ch * 8] =
          *(const s16x8*)&qkv[baseq + DD + (size_t)j * QS + ch * 8];
    }
    __syncthreads();
#pragma unroll
    for (int half = 0; half < 2; half++) {
      const int key = half * 16 + c;
      const bf16x8 kb0 = __builtin_bit_cast(bf16x8, *(const s16x8*)&kvs[wid][key * KP + g * 8]);
      const bf16x8 kb1 = __builtin_bit_cast(bf16x8, *(const s16x8*)&kvs[wid][key * KP + 32 + g * 8]);
      f32x4 a = {};
      a = __builtin_amdgcn_mfma_f32_16x16x32_bf16(__builtin_bit_cast(bf16x8, qf0), kb0, a, 0, 0, 0);
      a = __builtin_amdgcn_mfma_f32_16x16x32_bf16(__builtin_bit_cast(bf16x8, qf1), kb1, a, 0, 0, 0);
#pragma unroll
      for (int r = 0; r < 4; r++) {
        const int i = i0 + g * 4 + r;
        bool ok;
        if (isg) {
          ok = (key < ne);
        } else {
          const int j = kt0 + key;
          ok = (j <= i) && (((i - j) <= LOCAL_W) || ((j & (STRIDE_G - 1)) == 0));
        }
        const float s = ok ? a[r] * 0.125f : -1e30f;
        sc[t][half][r] = s;
        smax[r] = fmaxf(smax[r], s);
      }
    }
    __syncthreads();
  }
#pragma unroll
  for (int r = 0; r < 4; r++)
#pragma unroll
    for (int off = 8; off; off >>= 1)
      smax[r] = fmaxf(smax[r], __shfl_xor(smax[r], off));

  f32x4 o[4] = {};
  float lsum[4] = {0.f, 0.f, 0.f, 0.f};
#pragma unroll
  for (int t = 0; t < NTMAX; t++) {
    if (t > nlb) continue;
    const bool isg = (t == 0);
    if (isg && neb == 0) continue;
    const int kt0 = ka0 + (t - 1) * 32;
#pragma unroll
    for (int it = 0; it < 4; it++) {
      const int row = it * 8 + (lane >> 3);
      const int ch = lane & 7;
      const int j = isg ? ((row < ne) ? row * STRIDE_G : 0) : (kt0 + row);
      *(s16x8*)&kvs[wid][row * KP + ch * 8] =
          *(const s16x8*)&qkv[baseq + 2 * DD + (size_t)j * QS + ch * 8];
    }
#pragma unroll
    for (int half = 0; half < 2; half++)
#pragma unroll
      for (int r = 0; r < 4; r++) {
        const float p = __expf(sc[t][half][r] - smax[r]);
        lsum[r] += p;
        pls[wid][(g * 4 + r) * PP + half * 16 + c] = f2b(p);
      }
    __syncthreads();
    const bf16x8 pa = __builtin_bit_cast(bf16x8, *(const s16x8*)&pls[wid][c * PP + g * 8]);
#pragma unroll
    for (int d0 = 0; d0 < 4; d0++) {
      s16x8 bv;
#pragma unroll
      for (int e = 0; e < 8; e++)
        bv[e] = (short)kvs[wid][(g * 8 + e) * KP + d0 * 16 + c];
      o[d0] = __builtin_amdgcn_mfma_f32_16x16x32_bf16(pa, __builtin_bit_cast(bf16x8, bv), o[d0], 0, 0, 0);
    }
    __syncthreads();
  }
#pragma unroll
  for (int r = 0; r < 4; r++)
#pragma unroll
    for (int off = 8; off; off >>= 1)
      lsum[r] += __shfl_xor(lsum[r], off);
#pragma unroll
  for (int d0 = 0; d0 < 4; d0++)
#pragma unroll
    for (int r = 0; r < 4; r++)
      outg[baseo + (size_t)(i0 + g * 4 + r) * DD + d0 * 16 + c] = f2b(o[d0][r] / lsum[r]);
}

// ---------------- host ----------------
extern "C" void kernel_launch(void* const* d_in, const int* in_sizes, int n_in,
                              void* d_out, int out_size, void* d_ws, size_t ws_size,
                              hipStream_t stream) {
  const int* x = (const int*)d_in[0];
  const float* embed = (const float*)d_in[1];
  const float* pos = (const float*)d_in[2];
  const float* Wq = (const float*)d_in[3];
  const float* bq = (const float*)d_in[4];
  const float* Wk = (const float*)d_in[5];
  const float* bk = (const float*)d_in[6];
  const float* Wv = (const float*)d_in[7];
  const float* bv = (const float*)d_in[8];
  const float* Wo = (const float*)d_in[9];
  const float* bo = (const float*)d_in[10];
  const float* g1 = (const float*)d_in[11];
  const float* be1 = (const float*)d_in[12];
  const float* W1 = (const float*)d_in[13];
  const float* bf1 = (const float*)d_in[14];
  const float* W2 = (const float*)d_in[15];
  const float* bf2 = (const float*)d_in[16];
  const float* g2 = (const float*)d_in[17];
  const float* be2 = (const float*)d_in[18];
  const float* gf = (const float*)d_in[19];
  const float* bef = (const float*)d_in[20];
  const float* Whead = (const float*)d_in[21];

  char* ws = (char*)d_ws;
  size_t off = 0;
  auto alloc = [&](size_t bytes) -> void* {
    void* p = ws + off;
    off += (bytes + 255) & ~(size_t)255;
    return p;
  };
  unsigned short* WqkvT = (unsigned short*)alloc((size_t)2 * QS * DD * 2);
  unsigned short* WoT = (unsigned short*)alloc((size_t)2 * DD * DD * 2);
  unsigned short* W1T = (unsigned short*)alloc((size_t)2 * DD * FF * 2);
  unsigned short* W2T = (unsigned short*)alloc((size_t)2 * DD * FF * 2);
  unsigned short* WheadT = (unsigned short*)alloc((size_t)DD * VV * 2);
  float* bcat = (float*)alloc((size_t)2 * QS * 4);
  unsigned short* hb = (unsigned short*)alloc((size_t)MM * DD * 2);  // bf16 residual
  unsigned short* hn = (unsigned short*)alloc((size_t)MM * DD * 2);
  unsigned short* qkvb = (unsigned short*)alloc((size_t)MM * QS * 2);   // 24 MB
  unsigned short* attnb = (unsigned short*)alloc((size_t)MM * DD * 2);  // 8 MB
  unsigned short* mid = (unsigned short*)alloc((size_t)MM * FF * 2);    // 32 MB
  unsigned short* ffn2p = qkvb;   // 2 x [MM x DD] bf16 = 16 MB overlay (qkvb dead)
  unsigned short* oprojp = mid;   // 2 x [MM x DD] bf16 = 16 MB overlay (mid dead)
  unsigned short* headp = mid;    // 4 x [MM x VV] bf16 = 8 MB <= mid
  (void)ws_size;

  const dim3 tb(32, 8);
  qkv_t<<<dim3(DD / 32, DD / 32, 6), tb, 0, stream>>>(Wq, Wk, Wv, WqkvT);
  transpose_k<<<dim3(DD / 32, DD / 32, 2), tb, 0, stream>>>(Wo, WoT, DD, DD,
                                                            (size_t)DD * DD, (size_t)DD * DD);
  transpose_k<<<dim3(FF / 32, DD / 32, 2), tb, 0, stream>>>(W1, W1T, DD, FF,
                                                            (size_t)DD * FF, (size_t)DD * FF);
  transpose_k<<<dim3(DD / 32, FF / 32, 2), tb, 0, stream>>>(W2, W2T, FF, DD,
                                                            (size_t)DD * FF, (size_t)DD * FF);
  transpose_k<<<dim3(VV / 32, DD / 32, 1), tb, 0, stream>>>(Whead, WheadT, DD, VV, 0, 0);
  concat_bias<<<24, 256, 0, stream>>>(bq, bk, bv, bcat);

  embed_ln<<<MM, 256, 0, stream>>>(x, embed, pos, g1, be1, hb, hn);

  for (int l = 0; l < 2; l++) {
    const size_t wo = (size_t)l * DD * DD;
    const size_t wf = (size_t)l * DD * FF;
    // fused QKV: grid 384 = 8 * (16/4) * (24/2)
    gemm_dw3<1><<<(QS / 128) * (MM / 256), 512, 0, stream>>>(
        hn, WqkvT + (size_t)l * QS * DD, bcat + l * QS, qkvb,
        MM, QS, DD, QS / 128, MM / 256, 1, DD);
    attn_mfma<<<BB * HH * (TT / 64), 256, 0, stream>>>(qkvb, attnb);
    // O-proj: split-K=2, grid 256 -> bf16 partials in mid
    gemm_dw3<0><<<2 * (DD / 128) * (MM / 256), 512, 0, stream>>>(
        attnb, WoT + wo, nullptr, oprojp,
        MM, DD, DD, DD / 128, MM / 256, 2, DD / 2);
    ln_red<<<MM, 256, 0, stream>>>(hb, oprojp, bo + l * DD, g2 + l * DD, be2 + l * DD, hn);
    // FFN1: GELU, grid 512
    gemm_dw3<3><<<(FF / 128) * (MM / 256), 512, 0, stream>>>(
        hn, W1T + wf, bf1 + l * FF, mid,
        MM, FF, DD, FF / 128, MM / 256, 1, DD);
    // FFN2: split-K=2, grid 256 -> bf16 partials
    gemm_dw3<0><<<2 * (DD / 128) * (MM / 256), 512, 0, stream>>>(
        mid, W2T + wf, nullptr, ffn2p,
        MM, DD, FF, DD / 128, MM / 256, 2, FF / 2);
    if (l == 0)
      ln_red<<<MM, 256, 0, stream>>>(hb, ffn2p, bf2, g1 + DD, be1 + DD, hn);
    else
      ln_red<<<MM, 256, 0, stream>>>(hb, ffn2p, bf2 + DD, gf, bef, hn);
  }
  // head split-K=4 -> bf16 partials -> d_out (f32)
  gemm_p<<<4 * (VV / 128) * (MM / 128), 512, 0, stream>>>(
      hn, WheadT, headp, MM, VV, DD, VV / 128, (VV / 128) * (MM / 128), DD / 4);
  reduce_k<4><<<(MM * VV) / 1024, 256, 0, stream>>>(
      (float*)d_out, headp, (size_t)MM * VV);
}